// Round 2
// baseline (1201.814 us; speedup 1.0000x reference)
//
#include <hip/hip_runtime.h>

#define N_DIM 128
#define F_DIM 64

// ---------------- degree / sort kernels ----------------

__global__ __launch_bounds__(256) void k_count(const int* __restrict__ dst, int* __restrict__ cnt, int e) {
    int i = blockIdx.x * 256 + threadIdx.x;
    if (i < e) atomicAdd(&cnt[dst[i]], 1);
}

__global__ __launch_bounds__(256) void k_dinv(const int* __restrict__ cnt, float* __restrict__ dinv, int n) {
    int i = blockIdx.x * 256 + threadIdx.x;
    if (i < n) dinv[i] = rsqrtf((float)cnt[i] + 1.0f);   // +1 self loop
}

__global__ __launch_bounds__(256) void k_scan1(const int* __restrict__ cnt, int* __restrict__ excl,
                                               int* __restrict__ bsum, int n) {
    __shared__ int s[256];
    int t = threadIdx.x;
    int i = blockIdx.x * 256 + t;
    int v = (i < n) ? cnt[i] : 0;
    s[t] = v;
    __syncthreads();
    for (int off = 1; off < 256; off <<= 1) {
        int x = (t >= off) ? s[t - off] : 0;
        __syncthreads();
        s[t] += x;
        __syncthreads();
    }
    if (i < n) excl[i] = s[t] - v;
    if (t == 255) bsum[blockIdx.x] = s[255];
}

__global__ __launch_bounds__(512) void k_scan2(int* __restrict__ bsum, int nb, int* __restrict__ start, int n) {
    __shared__ int s[512];
    int t = threadIdx.x;
    int v = (t < nb) ? bsum[t] : 0;
    s[t] = v;
    __syncthreads();
    for (int off = 1; off < 512; off <<= 1) {
        int x = (t >= off) ? s[t - off] : 0;
        __syncthreads();
        s[t] += x;
        __syncthreads();
    }
    if (t < nb) bsum[t] = s[t] - v;     // exclusive block offsets
    if (t == 511) start[n] = s[511];    // total edge count
}

__global__ __launch_bounds__(256) void k_scan3(int* __restrict__ start, int* __restrict__ cursor,
                                               const int* __restrict__ bsum, int n) {
    int i = blockIdx.x * 256 + threadIdx.x;
    if (i < n) {
        int v = start[i] + bsum[blockIdx.x];
        start[i] = v;
        cursor[i] = v;
    }
}

__global__ __launch_bounds__(256) void k_place(const int* __restrict__ src, const int* __restrict__ dst,
                                               int* __restrict__ cursor, int* __restrict__ srcs, int e) {
    int i = blockIdx.x * 256 + threadIdx.x;
    if (i < e) {
        int slot = atomicAdd(&cursor[dst[i]], 1);
        srcs[slot] = src[i];
    }
}

// ---------------- GEMM: W columns in registers, h rows via global broadcast float4 ----------------

// u = dinv * (h @ W)   (N x 64) @ (64 x 64); lane holds W[:,lane] in 64 VGPRs
__global__ __launch_bounds__(256) void k_gemm_l(const float* __restrict__ H, const float* __restrict__ W,
                                                const float* __restrict__ dinv, float* __restrict__ U, int n) {
    int lane = threadIdx.x & 63;
    float w[64];
#pragma unroll
    for (int k = 0; k < 64; ++k) w[k] = W[k * F_DIM + lane];
    int gw = (blockIdx.x * 256 + threadIdx.x) >> 6;
    int nw = (gridDim.x * 256) >> 6;
    int ngrp = (n + 3) >> 2;
    for (int grp = gw; grp < ngrp; grp += nw) {
        int r0 = grp * 4;
        if (r0 + 4 <= n) {
            const float4* h0 = (const float4*)(H + (size_t)(r0 + 0) * F_DIM);
            const float4* h1 = (const float4*)(H + (size_t)(r0 + 1) * F_DIM);
            const float4* h2 = (const float4*)(H + (size_t)(r0 + 2) * F_DIM);
            const float4* h3 = (const float4*)(H + (size_t)(r0 + 3) * F_DIM);
            float a0 = 0.f, a1 = 0.f, a2 = 0.f, a3 = 0.f;
#pragma unroll 2
            for (int k4 = 0; k4 < 16; ++k4) {
                float4 v0 = h0[k4], v1 = h1[k4], v2 = h2[k4], v3 = h3[k4];
                a0 = fmaf(v0.x, w[4 * k4 + 0], a0); a0 = fmaf(v0.y, w[4 * k4 + 1], a0);
                a0 = fmaf(v0.z, w[4 * k4 + 2], a0); a0 = fmaf(v0.w, w[4 * k4 + 3], a0);
                a1 = fmaf(v1.x, w[4 * k4 + 0], a1); a1 = fmaf(v1.y, w[4 * k4 + 1], a1);
                a1 = fmaf(v1.z, w[4 * k4 + 2], a1); a1 = fmaf(v1.w, w[4 * k4 + 3], a1);
                a2 = fmaf(v2.x, w[4 * k4 + 0], a2); a2 = fmaf(v2.y, w[4 * k4 + 1], a2);
                a2 = fmaf(v2.z, w[4 * k4 + 2], a2); a2 = fmaf(v2.w, w[4 * k4 + 3], a2);
                a3 = fmaf(v3.x, w[4 * k4 + 0], a3); a3 = fmaf(v3.y, w[4 * k4 + 1], a3);
                a3 = fmaf(v3.z, w[4 * k4 + 2], a3); a3 = fmaf(v3.w, w[4 * k4 + 3], a3);
            }
            U[(size_t)(r0 + 0) * F_DIM + lane] = dinv[r0 + 0] * a0;
            U[(size_t)(r0 + 1) * F_DIM + lane] = dinv[r0 + 1] * a1;
            U[(size_t)(r0 + 2) * F_DIM + lane] = dinv[r0 + 2] * a2;
            U[(size_t)(r0 + 3) * F_DIM + lane] = dinv[r0 + 3] * a3;
        } else {
            for (int r = r0; r < n; ++r) {
                const float4* hr = (const float4*)(H + (size_t)r * F_DIM);
                float a = 0.f;
                for (int k4 = 0; k4 < 16; ++k4) {
                    float4 v = hr[k4];
                    a = fmaf(v.x, w[4 * k4 + 0], a); a = fmaf(v.y, w[4 * k4 + 1], a);
                    a = fmaf(v.z, w[4 * k4 + 2], a); a = fmaf(v.w, w[4 * k4 + 3], a);
                }
                U[(size_t)r * F_DIM + lane] = dinv[r] * a;
            }
        }
    }
}

// h = x @ W_pre + b_pre   (N x 128) @ (128 x 64); two k-passes, w[] reloaded per pass
__global__ __launch_bounds__(256) void k_gemm_pre(const float* __restrict__ X, const float* __restrict__ W,
                                                  const float* __restrict__ b, float* __restrict__ H, int n) {
    int lane = threadIdx.x & 63;
    float bj = b[lane];
    int gw = (blockIdx.x * 256 + threadIdx.x) >> 6;
    int nw = (gridDim.x * 256) >> 6;
    int ngrp = (n + 3) >> 2;
    for (int grp = gw; grp < ngrp; grp += nw) {
        int r0 = grp * 4;
        float a0 = bj, a1 = bj, a2 = bj, a3 = bj;
        if (r0 + 4 <= n) {
#pragma unroll 1
            for (int pass = 0; pass < 2; ++pass) {
                float w[64];
#pragma unroll
                for (int k = 0; k < 64; ++k) w[k] = W[(pass * 64 + k) * F_DIM + lane];
                const float4* h0 = (const float4*)(X + (size_t)(r0 + 0) * N_DIM + pass * 64);
                const float4* h1 = (const float4*)(X + (size_t)(r0 + 1) * N_DIM + pass * 64);
                const float4* h2 = (const float4*)(X + (size_t)(r0 + 2) * N_DIM + pass * 64);
                const float4* h3 = (const float4*)(X + (size_t)(r0 + 3) * N_DIM + pass * 64);
#pragma unroll 2
                for (int k4 = 0; k4 < 16; ++k4) {
                    float4 v0 = h0[k4], v1 = h1[k4], v2 = h2[k4], v3 = h3[k4];
                    a0 = fmaf(v0.x, w[4 * k4 + 0], a0); a0 = fmaf(v0.y, w[4 * k4 + 1], a0);
                    a0 = fmaf(v0.z, w[4 * k4 + 2], a0); a0 = fmaf(v0.w, w[4 * k4 + 3], a0);
                    a1 = fmaf(v1.x, w[4 * k4 + 0], a1); a1 = fmaf(v1.y, w[4 * k4 + 1], a1);
                    a1 = fmaf(v1.z, w[4 * k4 + 2], a1); a1 = fmaf(v1.w, w[4 * k4 + 3], a1);
                    a2 = fmaf(v2.x, w[4 * k4 + 0], a2); a2 = fmaf(v2.y, w[4 * k4 + 1], a2);
                    a2 = fmaf(v2.z, w[4 * k4 + 2], a2); a2 = fmaf(v2.w, w[4 * k4 + 3], a2);
                    a3 = fmaf(v3.x, w[4 * k4 + 0], a3); a3 = fmaf(v3.y, w[4 * k4 + 1], a3);
                    a3 = fmaf(v3.z, w[4 * k4 + 2], a3); a3 = fmaf(v3.w, w[4 * k4 + 3], a3);
                }
            }
            H[(size_t)(r0 + 0) * F_DIM + lane] = a0;
            H[(size_t)(r0 + 1) * F_DIM + lane] = a1;
            H[(size_t)(r0 + 2) * F_DIM + lane] = a2;
            H[(size_t)(r0 + 3) * F_DIM + lane] = a3;
        } else {
            for (int r = r0; r < n; ++r) {
                float a = bj;
                for (int pass = 0; pass < 2; ++pass) {
                    float w[64];
#pragma unroll
                    for (int k = 0; k < 64; ++k) w[k] = W[(pass * 64 + k) * F_DIM + lane];
                    const float4* hr = (const float4*)(X + (size_t)r * N_DIM + pass * 64);
                    for (int k4 = 0; k4 < 16; ++k4) {
                        float4 v = hr[k4];
                        a = fmaf(v.x, w[4 * k4 + 0], a); a = fmaf(v.y, w[4 * k4 + 1], a);
                        a = fmaf(v.z, w[4 * k4 + 2], a); a = fmaf(v.w, w[4 * k4 + 3], a);
                    }
                }
                H[(size_t)r * F_DIM + lane] = a;
            }
        }
    }
}

// ---------------- aggregation: wave per node, 4x16-lane groups, float4 row gather ----------------
// out[i] = epilogue( dinv[i]*(u[i] + sum_{src->i} u[src]) + b )
// MODE 0: relu -> out ; MODE 1: row L2-normalize -> out
template <int MODE>
__global__ __launch_bounds__(256) void k_agg(const float* __restrict__ U, const int* __restrict__ srcs,
                                             const int* __restrict__ start, const float* __restrict__ dinv,
                                             const float* __restrict__ bias, float* __restrict__ out, int n) {
    int node = blockIdx.x * 4 + (threadIdx.x >> 6);
    if (node >= n) return;
    int lane = threadIdx.x & 63;
    int g = lane >> 4;       // edge sub-group 0..3
    int t = lane & 15;       // float4 column slot
    const float4* U4 = (const float4*)U;

    int s0 = start[node];
    int s1 = start[node + 1];

    float4 acc = make_float4(0.f, 0.f, 0.f, 0.f);
    if (g == 0) acc = U4[(size_t)node * 16 + t];   // self-loop term

    for (int j = s0; j < s1; j += 64) {
        int cnt = min(64, s1 - j);
        int myidx = (lane < cnt) ? srcs[j + lane] : 0;
        for (int tb = 0; tb < cnt; tb += 16) {
            int e0 = tb + g, e1 = tb + 4 + g, e2 = tb + 8 + g, e3 = tb + 12 + g;
            int i0 = __shfl(myidx, e0);
            int i1 = __shfl(myidx, e1);
            int i2 = __shfl(myidx, e2);
            int i3 = __shfl(myidx, e3);
            float4 z = make_float4(0.f, 0.f, 0.f, 0.f);
            float4 v0 = (e0 < cnt) ? U4[(size_t)i0 * 16 + t] : z;
            float4 v1 = (e1 < cnt) ? U4[(size_t)i1 * 16 + t] : z;
            float4 v2 = (e2 < cnt) ? U4[(size_t)i2 * 16 + t] : z;
            float4 v3 = (e3 < cnt) ? U4[(size_t)i3 * 16 + t] : z;
            acc.x += (v0.x + v1.x) + (v2.x + v3.x);
            acc.y += (v0.y + v1.y) + (v2.y + v3.y);
            acc.z += (v0.z + v1.z) + (v2.z + v3.z);
            acc.w += (v0.w + v1.w) + (v2.w + v3.w);
        }
    }

    // reduce across the 4 groups (lanes ^16, ^32)
    acc.x += __shfl_xor(acc.x, 16); acc.x += __shfl_xor(acc.x, 32);
    acc.y += __shfl_xor(acc.y, 16); acc.y += __shfl_xor(acc.y, 32);
    acc.z += __shfl_xor(acc.z, 16); acc.z += __shfl_xor(acc.z, 32);
    acc.w += __shfl_xor(acc.w, 16); acc.w += __shfl_xor(acc.w, 32);

    float di = dinv[node];
    float4 bv = ((const float4*)bias)[t];
    float4 v;
    v.x = fmaf(di, acc.x, bv.x);
    v.y = fmaf(di, acc.y, bv.y);
    v.z = fmaf(di, acc.z, bv.z);
    v.w = fmaf(di, acc.w, bv.w);

    if (MODE == 0) {
        if (g == 0) {
            float4 r;
            r.x = fmaxf(v.x, 0.f); r.y = fmaxf(v.y, 0.f);
            r.z = fmaxf(v.z, 0.f); r.w = fmaxf(v.w, 0.f);
            ((float4*)out)[(size_t)node * 16 + t] = r;
        }
    } else {
        float ss = v.x * v.x + v.y * v.y + v.z * v.z + v.w * v.w;
        ss += __shfl_xor(ss, 1);
        ss += __shfl_xor(ss, 2);
        ss += __shfl_xor(ss, 4);
        ss += __shfl_xor(ss, 8);
        float inv = 1.0f / fmaxf(sqrtf(ss), 1e-12f);
        if (g == 0) {
            float4 r;
            r.x = v.x * inv; r.y = v.y * inv; r.z = v.z * inv; r.w = v.w * inv;
            ((float4*)out)[(size_t)node * 16 + t] = r;
        }
    }
}

// ---------------- launch ----------------

extern "C" void kernel_launch(void* const* d_in, const int* in_sizes, int n_in,
                              void* d_out, int out_size, void* d_ws, size_t ws_size,
                              hipStream_t stream) {
    const float* x     = (const float*)d_in[0];
    const int*   ei    = (const int*)d_in[1];
    const float* W_pre = (const float*)d_in[2];
    const float* b_pre = (const float*)d_in[3];
    const float* W1    = (const float*)d_in[4];
    const float* b1    = (const float*)d_in[5];
    const float* Wh    = (const float*)d_in[6];
    const float* bh    = (const float*)d_in[7];
    const float* Wo    = (const float*)d_in[8];
    const float* bo    = (const float*)d_in[9];

    int n = in_sizes[0] / N_DIM;   // 100000
    int e = in_sizes[1] / 2;       // 1600000
    const int* srcIdx = ei;
    const int* dstIdx = ei + e;

    // workspace carve-out
    size_t off = 0;
    auto alloc = [&](size_t bytes) -> void* {
        void* p = (char*)d_ws + off;
        off += (bytes + 255) & ~(size_t)255;
        return p;
    };
    int*   cnt    = (int*)alloc((size_t)n * 4);
    int*   start  = (int*)alloc((size_t)(n + 1) * 4);
    int*   cursor = (int*)alloc((size_t)n * 4);
    float* dinv   = (float*)alloc((size_t)n * 4);
    int*   bsum   = (int*)alloc(512 * 4);
    int*   srcs   = (int*)alloc((size_t)e * 4);
    float* h      = (float*)alloc((size_t)n * F_DIM * 4);
    float* u      = (float*)alloc((size_t)n * F_DIM * 4);

    int nbN = (n + 255) / 256;
    int nbE = (e + 255) / 256;

    // 1. degree count (without self loops)
    hipMemsetAsync(cnt, 0, (size_t)n * 4, stream);
    k_count<<<nbE, 256, 0, stream>>>(dstIdx, cnt, e);
    k_dinv<<<nbN, 256, 0, stream>>>(cnt, dinv, n);

    // 2. exclusive scan of counts -> start offsets, cursor copy
    k_scan1<<<nbN, 256, 0, stream>>>(cnt, start, bsum, n);
    k_scan2<<<1, 512, 0, stream>>>(bsum, nbN, start, n);
    k_scan3<<<nbN, 256, 0, stream>>>(start, cursor, bsum, n);

    // 3. place src indices sorted by dst
    k_place<<<nbE, 256, 0, stream>>>(srcIdx, dstIdx, cursor, srcs, e);

    // 4. feature_pre linear: h = x @ W_pre + b_pre
    k_gemm_pre<<<1024, 256, 0, stream>>>(x, W_pre, b_pre, h, n);

    // 5. layer 1
    k_gemm_l<<<1024, 256, 0, stream>>>(h, W1, dinv, u, n);
    k_agg<0><<<(n + 3) / 4, 256, 0, stream>>>(u, srcs, start, dinv, b1, h, n);

    // 6. layer 2
    k_gemm_l<<<1024, 256, 0, stream>>>(h, Wh, dinv, u, n);
    k_agg<0><<<(n + 3) / 4, 256, 0, stream>>>(u, srcs, start, dinv, bh, h, n);

    // 7. layer 3 + final row L2 normalize -> d_out
    k_gemm_l<<<1024, 256, 0, stream>>>(h, Wo, dinv, u, n);
    k_agg<1><<<(n + 3) / 4, 256, 0, stream>>>(u, srcs, start, dinv, bo, (float*)d_out, n);
}

// Round 3
// 914.859 us; speedup vs baseline: 1.3137x; 1.3137x over previous
//
#include <hip/hip_runtime.h>

#define N_DIM 128
#define F_DIM 64

// ---------------- degree / sort kernels ----------------

__global__ __launch_bounds__(256) void k_count(const int* __restrict__ dst, int* __restrict__ cnt, int e) {
    int i = blockIdx.x * 256 + threadIdx.x;
    if (i < e) atomicAdd(&cnt[dst[i]], 1);
}

__global__ __launch_bounds__(256) void k_dinv(const int* __restrict__ cnt, float* __restrict__ dinv, int n) {
    int i = blockIdx.x * 256 + threadIdx.x;
    if (i < n) dinv[i] = rsqrtf((float)cnt[i] + 1.0f);   // +1 self loop
}

__global__ __launch_bounds__(256) void k_scan1(const int* __restrict__ cnt, int* __restrict__ excl,
                                               int* __restrict__ bsum, int n) {
    __shared__ int s[256];
    int t = threadIdx.x;
    int i = blockIdx.x * 256 + t;
    int v = (i < n) ? cnt[i] : 0;
    s[t] = v;
    __syncthreads();
    for (int off = 1; off < 256; off <<= 1) {
        int x = (t >= off) ? s[t - off] : 0;
        __syncthreads();
        s[t] += x;
        __syncthreads();
    }
    if (i < n) excl[i] = s[t] - v;
    if (t == 255) bsum[blockIdx.x] = s[255];
}

__global__ __launch_bounds__(512) void k_scan2(int* __restrict__ bsum, int nb, int* __restrict__ start, int n) {
    __shared__ int s[512];
    int t = threadIdx.x;
    int v = (t < nb) ? bsum[t] : 0;
    s[t] = v;
    __syncthreads();
    for (int off = 1; off < 512; off <<= 1) {
        int x = (t >= off) ? s[t - off] : 0;
        __syncthreads();
        s[t] += x;
        __syncthreads();
    }
    if (t < nb) bsum[t] = s[t] - v;     // exclusive block offsets
    if (t == 511) start[n] = s[511];    // total edge count
}

__global__ __launch_bounds__(256) void k_scan3(int* __restrict__ start, int* __restrict__ cursor,
                                               const int* __restrict__ bsum, int n) {
    int i = blockIdx.x * 256 + threadIdx.x;
    if (i < n) {
        int v = start[i] + bsum[blockIdx.x];
        start[i] = v;
        cursor[i] = v;
    }
}

__global__ __launch_bounds__(256) void k_place(const int* __restrict__ src, const int* __restrict__ dst,
                                               int* __restrict__ cursor, int* __restrict__ srcs, int e) {
    int i = blockIdx.x * 256 + threadIdx.x;
    if (i < e) {
        int slot = atomicAdd(&cursor[dst[i]], 1);
        srcs[slot] = src[i];
    }
}

// ---------------- GEMM: W columns in registers (compile-time indexed), h rows via
// wave-uniform broadcast float4 loads. FULL unroll so w[] never touches scratch. ------------

#define FMA4(ACC, V, KB)                                        \
    ACC = fmaf((V).x, w[4 * (KB) + 0], ACC);                    \
    ACC = fmaf((V).y, w[4 * (KB) + 1], ACC);                    \
    ACC = fmaf((V).z, w[4 * (KB) + 2], ACC);                    \
    ACC = fmaf((V).w, w[4 * (KB) + 3], ACC);

// u = dinv * (h @ W)   (N x 64) @ (64 x 64); lane holds W[:,lane] in 64 VGPRs
__global__ __launch_bounds__(256, 4) void k_gemm_l(const float* __restrict__ H, const float* __restrict__ W,
                                                   const float* __restrict__ dinv, float* __restrict__ U, int n) {
    int lane = threadIdx.x & 63;
    float w[64];
#pragma unroll
    for (int k = 0; k < 64; ++k) w[k] = W[k * F_DIM + lane];
    int gw = (blockIdx.x * 256 + threadIdx.x) >> 6;
    int nw = (gridDim.x * 256) >> 6;
    int ngrp = (n + 1) >> 1;
    for (int grp = gw; grp < ngrp; grp += nw) {
        int r0 = grp * 2;
        const float4* h0 = (const float4*)(H + (size_t)r0 * F_DIM);
        if (r0 + 2 <= n) {
            const float4* h1 = (const float4*)(H + (size_t)(r0 + 1) * F_DIM);
            float a0 = 0.f, b0 = 0.f, a1 = 0.f, b1 = 0.f;
#pragma unroll
            for (int k4 = 0; k4 < 8; ++k4) {
                float4 v0 = h0[2 * k4], u0 = h0[2 * k4 + 1];
                float4 v1 = h1[2 * k4], u1 = h1[2 * k4 + 1];
                FMA4(a0, v0, 2 * k4); FMA4(b0, u0, 2 * k4 + 1);
                FMA4(a1, v1, 2 * k4); FMA4(b1, u1, 2 * k4 + 1);
            }
            U[(size_t)(r0 + 0) * F_DIM + lane] = dinv[r0 + 0] * (a0 + b0);
            U[(size_t)(r0 + 1) * F_DIM + lane] = dinv[r0 + 1] * (a1 + b1);
        } else {
            float a0 = 0.f, b0 = 0.f;
#pragma unroll
            for (int k4 = 0; k4 < 8; ++k4) {
                float4 v0 = h0[2 * k4], u0 = h0[2 * k4 + 1];
                FMA4(a0, v0, 2 * k4); FMA4(b0, u0, 2 * k4 + 1);
            }
            U[(size_t)r0 * F_DIM + lane] = dinv[r0] * (a0 + b0);
        }
    }
}

// h = x @ W_pre + b_pre   (N x 128) @ (128 x 64); two k-passes, w[] reloaded per pass
__global__ __launch_bounds__(256, 4) void k_gemm_pre(const float* __restrict__ X, const float* __restrict__ W,
                                                     const float* __restrict__ b, float* __restrict__ H, int n) {
    int lane = threadIdx.x & 63;
    float bj = b[lane];
    int gw = (blockIdx.x * 256 + threadIdx.x) >> 6;
    int nw = (gridDim.x * 256) >> 6;
    int ngrp = (n + 1) >> 1;
    for (int grp = gw; grp < ngrp; grp += nw) {
        int r0 = grp * 2;
        bool two = (r0 + 2 <= n);
        float a0 = bj, b0 = 0.f, a1 = bj, b1 = 0.f;
#pragma unroll 1
        for (int pass = 0; pass < 2; ++pass) {
            float w[64];
#pragma unroll
            for (int k = 0; k < 64; ++k) w[k] = W[(pass * 64 + k) * F_DIM + lane];
            const float4* h0 = (const float4*)(X + (size_t)r0 * N_DIM + pass * 64);
            const float4* h1 = (const float4*)(X + (size_t)(r0 + (two ? 1 : 0)) * N_DIM + pass * 64);
#pragma unroll
            for (int k4 = 0; k4 < 8; ++k4) {
                float4 v0 = h0[2 * k4], u0 = h0[2 * k4 + 1];
                float4 v1 = h1[2 * k4], u1 = h1[2 * k4 + 1];
                FMA4(a0, v0, 2 * k4); FMA4(b0, u0, 2 * k4 + 1);
                FMA4(a1, v1, 2 * k4); FMA4(b1, u1, 2 * k4 + 1);
            }
        }
        H[(size_t)r0 * F_DIM + lane] = a0 + b0;
        if (two) H[(size_t)(r0 + 1) * F_DIM + lane] = a1 + b1;
    }
}

// ---------------- aggregation: wave per node, 4x16-lane groups, float4 row gather ----------------
// out[i] = epilogue( dinv[i]*(u[i] + sum_{src->i} u[src]) + b )
// MODE 0: relu -> out ; MODE 1: row L2-normalize -> out
template <int MODE>
__global__ __launch_bounds__(256) void k_agg(const float* __restrict__ U, const int* __restrict__ srcs,
                                             const int* __restrict__ start, const float* __restrict__ dinv,
                                             const float* __restrict__ bias, float* __restrict__ out, int n) {
    int node = blockIdx.x * 4 + (threadIdx.x >> 6);
    if (node >= n) return;
    int lane = threadIdx.x & 63;
    int g = lane >> 4;       // edge sub-group 0..3
    int t = lane & 15;       // float4 column slot
    const float4* U4 = (const float4*)U;

    int s0 = start[node];
    int s1 = start[node + 1];

    float4 acc = make_float4(0.f, 0.f, 0.f, 0.f);
    if (g == 0) acc = U4[(size_t)node * 16 + t];   // self-loop term

    for (int j = s0; j < s1; j += 64) {
        int cnt = min(64, s1 - j);
        int myidx = (lane < cnt) ? srcs[j + lane] : 0;
        for (int tb = 0; tb < cnt; tb += 16) {
            int e0 = tb + g, e1 = tb + 4 + g, e2 = tb + 8 + g, e3 = tb + 12 + g;
            int i0 = __shfl(myidx, e0);
            int i1 = __shfl(myidx, e1);
            int i2 = __shfl(myidx, e2);
            int i3 = __shfl(myidx, e3);
            float4 z = make_float4(0.f, 0.f, 0.f, 0.f);
            float4 v0 = (e0 < cnt) ? U4[(size_t)i0 * 16 + t] : z;
            float4 v1 = (e1 < cnt) ? U4[(size_t)i1 * 16 + t] : z;
            float4 v2 = (e2 < cnt) ? U4[(size_t)i2 * 16 + t] : z;
            float4 v3 = (e3 < cnt) ? U4[(size_t)i3 * 16 + t] : z;
            acc.x += (v0.x + v1.x) + (v2.x + v3.x);
            acc.y += (v0.y + v1.y) + (v2.y + v3.y);
            acc.z += (v0.z + v1.z) + (v2.z + v3.z);
            acc.w += (v0.w + v1.w) + (v2.w + v3.w);
        }
    }

    // reduce across the 4 groups (lanes ^16, ^32)
    acc.x += __shfl_xor(acc.x, 16); acc.x += __shfl_xor(acc.x, 32);
    acc.y += __shfl_xor(acc.y, 16); acc.y += __shfl_xor(acc.y, 32);
    acc.z += __shfl_xor(acc.z, 16); acc.z += __shfl_xor(acc.z, 32);
    acc.w += __shfl_xor(acc.w, 16); acc.w += __shfl_xor(acc.w, 32);

    float di = dinv[node];
    float4 bv = ((const float4*)bias)[t];
    float4 v;
    v.x = fmaf(di, acc.x, bv.x);
    v.y = fmaf(di, acc.y, bv.y);
    v.z = fmaf(di, acc.z, bv.z);
    v.w = fmaf(di, acc.w, bv.w);

    if (MODE == 0) {
        if (g == 0) {
            float4 r;
            r.x = fmaxf(v.x, 0.f); r.y = fmaxf(v.y, 0.f);
            r.z = fmaxf(v.z, 0.f); r.w = fmaxf(v.w, 0.f);
            ((float4*)out)[(size_t)node * 16 + t] = r;
        }
    } else {
        float ss = v.x * v.x + v.y * v.y + v.z * v.z + v.w * v.w;
        ss += __shfl_xor(ss, 1);
        ss += __shfl_xor(ss, 2);
        ss += __shfl_xor(ss, 4);
        ss += __shfl_xor(ss, 8);
        float inv = 1.0f / fmaxf(sqrtf(ss), 1e-12f);
        if (g == 0) {
            float4 r;
            r.x = v.x * inv; r.y = v.y * inv; r.z = v.z * inv; r.w = v.w * inv;
            ((float4*)out)[(size_t)node * 16 + t] = r;
        }
    }
}

// ---------------- launch ----------------

extern "C" void kernel_launch(void* const* d_in, const int* in_sizes, int n_in,
                              void* d_out, int out_size, void* d_ws, size_t ws_size,
                              hipStream_t stream) {
    const float* x     = (const float*)d_in[0];
    const int*   ei    = (const int*)d_in[1];
    const float* W_pre = (const float*)d_in[2];
    const float* b_pre = (const float*)d_in[3];
    const float* W1    = (const float*)d_in[4];
    const float* b1    = (const float*)d_in[5];
    const float* Wh    = (const float*)d_in[6];
    const float* bh    = (const float*)d_in[7];
    const float* Wo    = (const float*)d_in[8];
    const float* bo    = (const float*)d_in[9];

    int n = in_sizes[0] / N_DIM;   // 100000
    int e = in_sizes[1] / 2;       // 1600000
    const int* srcIdx = ei;
    const int* dstIdx = ei + e;

    // workspace carve-out
    size_t off = 0;
    auto alloc = [&](size_t bytes) -> void* {
        void* p = (char*)d_ws + off;
        off += (bytes + 255) & ~(size_t)255;
        return p;
    };
    int*   cnt    = (int*)alloc((size_t)n * 4);
    int*   start  = (int*)alloc((size_t)(n + 1) * 4);
    int*   cursor = (int*)alloc((size_t)n * 4);
    float* dinv   = (float*)alloc((size_t)n * 4);
    int*   bsum   = (int*)alloc(512 * 4);
    int*   srcs   = (int*)alloc((size_t)e * 4);
    float* h      = (float*)alloc((size_t)n * F_DIM * 4);
    float* u      = (float*)alloc((size_t)n * F_DIM * 4);

    int nbN = (n + 255) / 256;
    int nbE = (e + 255) / 256;

    // 1. degree count (without self loops)
    hipMemsetAsync(cnt, 0, (size_t)n * 4, stream);
    k_count<<<nbE, 256, 0, stream>>>(dstIdx, cnt, e);
    k_dinv<<<nbN, 256, 0, stream>>>(cnt, dinv, n);

    // 2. exclusive scan of counts -> start offsets, cursor copy
    k_scan1<<<nbN, 256, 0, stream>>>(cnt, start, bsum, n);
    k_scan2<<<1, 512, 0, stream>>>(bsum, nbN, start, n);
    k_scan3<<<nbN, 256, 0, stream>>>(start, cursor, bsum, n);

    // 3. place src indices sorted by dst
    k_place<<<nbE, 256, 0, stream>>>(srcIdx, dstIdx, cursor, srcs, e);

    // 4. feature_pre linear: h = x @ W_pre + b_pre
    k_gemm_pre<<<2048, 256, 0, stream>>>(x, W_pre, b_pre, h, n);

    // 5. layer 1
    k_gemm_l<<<2048, 256, 0, stream>>>(h, W1, dinv, u, n);
    k_agg<0><<<(n + 3) / 4, 256, 0, stream>>>(u, srcs, start, dinv, b1, h, n);

    // 6. layer 2
    k_gemm_l<<<2048, 256, 0, stream>>>(h, Wh, dinv, u, n);
    k_agg<0><<<(n + 3) / 4, 256, 0, stream>>>(u, srcs, start, dinv, bh, h, n);

    // 7. layer 3 + final row L2 normalize -> d_out
    k_gemm_l<<<2048, 256, 0, stream>>>(h, Wo, dinv, u, n);
    k_agg<1><<<(n + 3) / 4, 256, 0, stream>>>(u, srcs, start, dinv, bo, (float*)d_out, n);
}

// Round 4
// 892.991 us; speedup vs baseline: 1.3458x; 1.0245x over previous
//
#include <hip/hip_runtime.h>

#define N_DIM 128
#define F_DIM 64

// ---------------- degree / sort kernels ----------------

__global__ __launch_bounds__(256) void k_count(const int* __restrict__ dst, int* __restrict__ cnt, int e) {
    int i = blockIdx.x * 256 + threadIdx.x;
    if (i < e) atomicAdd(&cnt[dst[i]], 1);
}

__global__ __launch_bounds__(256) void k_dinv(const int* __restrict__ cnt, float* __restrict__ dinv, int n) {
    int i = blockIdx.x * 256 + threadIdx.x;
    if (i < n) dinv[i] = rsqrtf((float)cnt[i] + 1.0f);   // +1 self loop
}

__global__ __launch_bounds__(256) void k_scan1(const int* __restrict__ cnt, int* __restrict__ excl,
                                               int* __restrict__ bsum, int n) {
    __shared__ int s[256];
    int t = threadIdx.x;
    int i = blockIdx.x * 256 + t;
    int v = (i < n) ? cnt[i] : 0;
    s[t] = v;
    __syncthreads();
    for (int off = 1; off < 256; off <<= 1) {
        int x = (t >= off) ? s[t - off] : 0;
        __syncthreads();
        s[t] += x;
        __syncthreads();
    }
    if (i < n) excl[i] = s[t] - v;
    if (t == 255) bsum[blockIdx.x] = s[255];
}

__global__ __launch_bounds__(512) void k_scan2(int* __restrict__ bsum, int nb, int* __restrict__ start, int n) {
    __shared__ int s[512];
    int t = threadIdx.x;
    int v = (t < nb) ? bsum[t] : 0;
    s[t] = v;
    __syncthreads();
    for (int off = 1; off < 512; off <<= 1) {
        int x = (t >= off) ? s[t - off] : 0;
        __syncthreads();
        s[t] += x;
        __syncthreads();
    }
    if (t < nb) bsum[t] = s[t] - v;     // exclusive block offsets
    if (t == 511) start[n] = s[511];    // total edge count
}

__global__ __launch_bounds__(256) void k_scan3(int* __restrict__ start, int* __restrict__ cursor,
                                               const int* __restrict__ bsum, int n) {
    int i = blockIdx.x * 256 + threadIdx.x;
    if (i < n) {
        int v = start[i] + bsum[blockIdx.x];
        start[i] = v;
        cursor[i] = v;
    }
}

__global__ __launch_bounds__(256) void k_place(const int* __restrict__ src, const int* __restrict__ dst,
                                               int* __restrict__ cursor, int* __restrict__ srcs, int e) {
    int i = blockIdx.x * 256 + threadIdx.x;
    if (i < e) {
        int slot = atomicAdd(&cursor[dst[i]], 1);
        srcs[slot] = src[i];
    }
}

// ---------------- GEMM: W transposed in LDS (ds_read_b128 per 4 weights),
// h rows via wave-uniform broadcast float4 global loads, 4 rows/wave-group ----------------

#define FMA4W(ACC, V, WV)                 \
    ACC = fmaf((V).x, (WV).x, ACC);       \
    ACC = fmaf((V).y, (WV).y, ACC);       \
    ACC = fmaf((V).z, (WV).z, ACC);       \
    ACC = fmaf((V).w, (WV).w, ACC);

// u = dinv * (h @ W)   (N x 64) @ (64 x 64)
__global__ __launch_bounds__(256) void k_gemm_l(const float* __restrict__ H, const float* __restrict__ W,
                                                const float* __restrict__ dinv, float* __restrict__ U, int n) {
    __shared__ float WT[64 * 68];          // WT[c][k], stride 68 (16B-aligned rows)
    for (int i = threadIdx.x; i < 64 * 64; i += 256) {
        int k = i >> 6, c = i & 63;
        WT[c * 68 + k] = W[i];             // W[k][c], coalesced read
    }
    __syncthreads();
    int lane = threadIdx.x & 63;
    const float* wl = &WT[lane * 68];
    int gw = (blockIdx.x * 256 + threadIdx.x) >> 6;
    int nw = (gridDim.x * 256) >> 6;
    int ngrp = (n + 3) >> 2;
    for (int grp = gw; grp < ngrp; grp += nw) {
        int r0 = grp * 4;
        int r1 = min(r0 + 1, n - 1), r2 = min(r0 + 2, n - 1), r3 = min(r0 + 3, n - 1);
        const float4* h0 = (const float4*)(H + (size_t)r0 * F_DIM);
        const float4* h1 = (const float4*)(H + (size_t)r1 * F_DIM);
        const float4* h2 = (const float4*)(H + (size_t)r2 * F_DIM);
        const float4* h3 = (const float4*)(H + (size_t)r3 * F_DIM);
        float a0 = 0.f, a1 = 0.f, a2 = 0.f, a3 = 0.f;
#pragma unroll
        for (int k4 = 0; k4 < 16; ++k4) {
            float4 wv = *(const float4*)(wl + 4 * k4);
            float4 v0 = h0[k4], v1 = h1[k4], v2 = h2[k4], v3 = h3[k4];
            FMA4W(a0, v0, wv); FMA4W(a1, v1, wv);
            FMA4W(a2, v2, wv); FMA4W(a3, v3, wv);
        }
        U[(size_t)r0 * F_DIM + lane] = dinv[r0] * a0;
        if (r0 + 1 < n) U[(size_t)(r0 + 1) * F_DIM + lane] = dinv[r0 + 1] * a1;
        if (r0 + 2 < n) U[(size_t)(r0 + 2) * F_DIM + lane] = dinv[r0 + 2] * a2;
        if (r0 + 3 < n) U[(size_t)(r0 + 3) * F_DIM + lane] = dinv[r0 + 3] * a3;
    }
}

// h = x @ W_pre + b_pre   (N x 128) @ (128 x 64)
__global__ __launch_bounds__(256) void k_gemm_pre(const float* __restrict__ X, const float* __restrict__ W,
                                                  const float* __restrict__ b, float* __restrict__ H, int n) {
    __shared__ float WT[64 * 132];         // WT[c][k], k=0..127, stride 132
    for (int i = threadIdx.x; i < 128 * 64; i += 256) {
        int k = i >> 6, c = i & 63;
        WT[c * 132 + k] = W[i];
    }
    __syncthreads();
    int lane = threadIdx.x & 63;
    float bj = b[lane];
    const float* wl = &WT[lane * 132];
    int gw = (blockIdx.x * 256 + threadIdx.x) >> 6;
    int nw = (gridDim.x * 256) >> 6;
    int ngrp = (n + 3) >> 2;
    for (int grp = gw; grp < ngrp; grp += nw) {
        int r0 = grp * 4;
        int r1 = min(r0 + 1, n - 1), r2 = min(r0 + 2, n - 1), r3 = min(r0 + 3, n - 1);
        const float4* h0 = (const float4*)(X + (size_t)r0 * N_DIM);
        const float4* h1 = (const float4*)(X + (size_t)r1 * N_DIM);
        const float4* h2 = (const float4*)(X + (size_t)r2 * N_DIM);
        const float4* h3 = (const float4*)(X + (size_t)r3 * N_DIM);
        float a0 = bj, a1 = bj, a2 = bj, a3 = bj;
#pragma unroll
        for (int k4 = 0; k4 < 32; ++k4) {
            float4 wv = *(const float4*)(wl + 4 * k4);
            float4 v0 = h0[k4], v1 = h1[k4], v2 = h2[k4], v3 = h3[k4];
            FMA4W(a0, v0, wv); FMA4W(a1, v1, wv);
            FMA4W(a2, v2, wv); FMA4W(a3, v3, wv);
        }
        H[(size_t)r0 * F_DIM + lane] = a0;
        if (r0 + 1 < n) H[(size_t)(r0 + 1) * F_DIM + lane] = a1;
        if (r0 + 2 < n) H[(size_t)(r0 + 2) * F_DIM + lane] = a2;
        if (r0 + 3 < n) H[(size_t)(r0 + 3) * F_DIM + lane] = a3;
    }
}

// ---------------- aggregation: wave per node, 4x16-lane groups, direct broadcast index
// loads (no shfl), 32 edges / 8 row-loads in flight per iteration ----------------
// out[i] = epilogue( dinv[i]*(u[i] + sum_{src->i} u[src]) + b )
// MODE 0: relu -> out ; MODE 1: row L2-normalize -> out
template <int MODE>
__global__ __launch_bounds__(256) void k_agg(const float* __restrict__ U, const int* __restrict__ srcs,
                                             const int* __restrict__ start, const float* __restrict__ dinv,
                                             const float* __restrict__ bias, float* __restrict__ out, int n) {
    int node = blockIdx.x * 4 + (threadIdx.x >> 6);
    if (node >= n) return;
    int lane = threadIdx.x & 63;
    int g = lane >> 4;       // edge sub-slot 0..3
    int t = lane & 15;       // float4 column slot
    const float4* U4 = (const float4*)U;

    int s0 = start[node];
    int s1 = start[node + 1];

    float4 z = make_float4(0.f, 0.f, 0.f, 0.f);
    float4 acc = (g == 0) ? U4[(size_t)node * 16 + t] : z;   // self-loop term
    float4 acc2 = z;

    for (int p = s0; p < s1; p += 32) {
        int e0 = p + g, e1 = p + 4 + g, e2 = p + 8 + g, e3 = p + 12 + g;
        int e4 = p + 16 + g, e5 = p + 20 + g, e6 = p + 24 + g, e7 = p + 28 + g;
        // broadcast index loads (uniform within 16-lane group)
        int i0 = (e0 < s1) ? srcs[e0] : 0;
        int i1 = (e1 < s1) ? srcs[e1] : 0;
        int i2 = (e2 < s1) ? srcs[e2] : 0;
        int i3 = (e3 < s1) ? srcs[e3] : 0;
        int i4 = (e4 < s1) ? srcs[e4] : 0;
        int i5 = (e5 < s1) ? srcs[e5] : 0;
        int i6 = (e6 < s1) ? srcs[e6] : 0;
        int i7 = (e7 < s1) ? srcs[e7] : 0;
        float4 v0 = (e0 < s1) ? U4[(size_t)i0 * 16 + t] : z;
        float4 v1 = (e1 < s1) ? U4[(size_t)i1 * 16 + t] : z;
        float4 v2 = (e2 < s1) ? U4[(size_t)i2 * 16 + t] : z;
        float4 v3 = (e3 < s1) ? U4[(size_t)i3 * 16 + t] : z;
        float4 v4 = (e4 < s1) ? U4[(size_t)i4 * 16 + t] : z;
        float4 v5 = (e5 < s1) ? U4[(size_t)i5 * 16 + t] : z;
        float4 v6 = (e6 < s1) ? U4[(size_t)i6 * 16 + t] : z;
        float4 v7 = (e7 < s1) ? U4[(size_t)i7 * 16 + t] : z;
        acc.x += (v0.x + v1.x) + (v2.x + v3.x);
        acc.y += (v0.y + v1.y) + (v2.y + v3.y);
        acc.z += (v0.z + v1.z) + (v2.z + v3.z);
        acc.w += (v0.w + v1.w) + (v2.w + v3.w);
        acc2.x += (v4.x + v5.x) + (v6.x + v7.x);
        acc2.y += (v4.y + v5.y) + (v6.y + v7.y);
        acc2.z += (v4.z + v5.z) + (v6.z + v7.z);
        acc2.w += (v4.w + v5.w) + (v6.w + v7.w);
    }
    acc.x += acc2.x; acc.y += acc2.y; acc.z += acc2.z; acc.w += acc2.w;

    // reduce across the 4 sub-slots (lanes ^16, ^32)
    acc.x += __shfl_xor(acc.x, 16); acc.x += __shfl_xor(acc.x, 32);
    acc.y += __shfl_xor(acc.y, 16); acc.y += __shfl_xor(acc.y, 32);
    acc.z += __shfl_xor(acc.z, 16); acc.z += __shfl_xor(acc.z, 32);
    acc.w += __shfl_xor(acc.w, 16); acc.w += __shfl_xor(acc.w, 32);

    float di = dinv[node];
    float4 bv = ((const float4*)bias)[t];
    float4 v;
    v.x = fmaf(di, acc.x, bv.x);
    v.y = fmaf(di, acc.y, bv.y);
    v.z = fmaf(di, acc.z, bv.z);
    v.w = fmaf(di, acc.w, bv.w);

    if (MODE == 0) {
        if (g == 0) {
            float4 r;
            r.x = fmaxf(v.x, 0.f); r.y = fmaxf(v.y, 0.f);
            r.z = fmaxf(v.z, 0.f); r.w = fmaxf(v.w, 0.f);
            ((float4*)out)[(size_t)node * 16 + t] = r;
        }
    } else {
        float ss = v.x * v.x + v.y * v.y + v.z * v.z + v.w * v.w;
        ss += __shfl_xor(ss, 1);
        ss += __shfl_xor(ss, 2);
        ss += __shfl_xor(ss, 4);
        ss += __shfl_xor(ss, 8);
        float inv = 1.0f / fmaxf(sqrtf(ss), 1e-12f);
        if (g == 0) {
            float4 r;
            r.x = v.x * inv; r.y = v.y * inv; r.z = v.z * inv; r.w = v.w * inv;
            ((float4*)out)[(size_t)node * 16 + t] = r;
        }
    }
}

// ---------------- launch ----------------

extern "C" void kernel_launch(void* const* d_in, const int* in_sizes, int n_in,
                              void* d_out, int out_size, void* d_ws, size_t ws_size,
                              hipStream_t stream) {
    const float* x     = (const float*)d_in[0];
    const int*   ei    = (const int*)d_in[1];
    const float* W_pre = (const float*)d_in[2];
    const float* b_pre = (const float*)d_in[3];
    const float* W1    = (const float*)d_in[4];
    const float* b1    = (const float*)d_in[5];
    const float* Wh    = (const float*)d_in[6];
    const float* bh    = (const float*)d_in[7];
    const float* Wo    = (const float*)d_in[8];
    const float* bo    = (const float*)d_in[9];

    int n = in_sizes[0] / N_DIM;   // 100000
    int e = in_sizes[1] / 2;       // 1600000
    const int* srcIdx = ei;
    const int* dstIdx = ei + e;

    // workspace carve-out
    size_t off = 0;
    auto alloc = [&](size_t bytes) -> void* {
        void* p = (char*)d_ws + off;
        off += (bytes + 255) & ~(size_t)255;
        return p;
    };
    int*   cnt    = (int*)alloc((size_t)n * 4);
    int*   start  = (int*)alloc((size_t)(n + 1) * 4);
    int*   cursor = (int*)alloc((size_t)n * 4);
    float* dinv   = (float*)alloc((size_t)n * 4);
    int*   bsum   = (int*)alloc(512 * 4);
    int*   srcs   = (int*)alloc((size_t)e * 4);
    float* h      = (float*)alloc((size_t)n * F_DIM * 4);
    float* u      = (float*)alloc((size_t)n * F_DIM * 4);

    int nbN = (n + 255) / 256;
    int nbE = (e + 255) / 256;

    // 1. degree count (without self loops)
    hipMemsetAsync(cnt, 0, (size_t)n * 4, stream);
    k_count<<<nbE, 256, 0, stream>>>(dstIdx, cnt, e);
    k_dinv<<<nbN, 256, 0, stream>>>(cnt, dinv, n);

    // 2. exclusive scan of counts -> start offsets, cursor copy
    k_scan1<<<nbN, 256, 0, stream>>>(cnt, start, bsum, n);
    k_scan2<<<1, 512, 0, stream>>>(bsum, nbN, start, n);
    k_scan3<<<nbN, 256, 0, stream>>>(start, cursor, bsum, n);

    // 3. place src indices sorted by dst
    k_place<<<nbE, 256, 0, stream>>>(srcIdx, dstIdx, cursor, srcs, e);

    // 4. feature_pre linear: h = x @ W_pre + b_pre
    k_gemm_pre<<<2048, 256, 0, stream>>>(x, W_pre, b_pre, h, n);

    // 5. layer 1
    k_gemm_l<<<2048, 256, 0, stream>>>(h, W1, dinv, u, n);
    k_agg<0><<<(n + 3) / 4, 256, 0, stream>>>(u, srcs, start, dinv, b1, h, n);

    // 6. layer 2
    k_gemm_l<<<2048, 256, 0, stream>>>(h, Wh, dinv, u, n);
    k_agg<0><<<(n + 3) / 4, 256, 0, stream>>>(u, srcs, start, dinv, bh, h, n);

    // 7. layer 3 + final row L2 normalize -> d_out
    k_gemm_l<<<2048, 256, 0, stream>>>(h, Wo, dinv, u, n);
    k_agg<1><<<(n + 3) / 4, 256, 0, stream>>>(u, srcs, start, dinv, bo, (float*)d_out, n);
}

// Round 5
// 803.179 us; speedup vs baseline: 1.4963x; 1.1118x over previous
//
#include <hip/hip_runtime.h>

#define N_DIM 128
#define F_DIM 64

// ---------------- degree / sort kernels ----------------

__global__ __launch_bounds__(256) void k_count(const int* __restrict__ dst, int* __restrict__ cnt, int e) {
    int i = blockIdx.x * 256 + threadIdx.x;
    if (i < e) atomicAdd(&cnt[dst[i]], 1);
}

__global__ __launch_bounds__(256) void k_dinv(const int* __restrict__ cnt, float* __restrict__ dinv, int n) {
    int i = blockIdx.x * 256 + threadIdx.x;
    if (i < n) dinv[i] = rsqrtf((float)cnt[i] + 1.0f);   // +1 self loop
}

__global__ __launch_bounds__(256) void k_scan1(const int* __restrict__ cnt, int* __restrict__ excl,
                                               int* __restrict__ bsum, int n) {
    __shared__ int s[256];
    int t = threadIdx.x;
    int i = blockIdx.x * 256 + t;
    int v = (i < n) ? cnt[i] : 0;
    s[t] = v;
    __syncthreads();
    for (int off = 1; off < 256; off <<= 1) {
        int x = (t >= off) ? s[t - off] : 0;
        __syncthreads();
        s[t] += x;
        __syncthreads();
    }
    if (i < n) excl[i] = s[t] - v;
    if (t == 255) bsum[blockIdx.x] = s[255];
}

__global__ __launch_bounds__(512) void k_scan2(int* __restrict__ bsum, int nb, int* __restrict__ start, int n) {
    __shared__ int s[512];
    int t = threadIdx.x;
    int v = (t < nb) ? bsum[t] : 0;
    s[t] = v;
    __syncthreads();
    for (int off = 1; off < 512; off <<= 1) {
        int x = (t >= off) ? s[t - off] : 0;
        __syncthreads();
        s[t] += x;
        __syncthreads();
    }
    if (t < nb) bsum[t] = s[t] - v;     // exclusive block offsets
    if (t == 511) start[n] = s[511];    // total edge count
}

__global__ __launch_bounds__(256) void k_scan3(int* __restrict__ start, int* __restrict__ cursor,
                                               const int* __restrict__ bsum, int n) {
    int i = blockIdx.x * 256 + threadIdx.x;
    if (i < n) {
        int v = start[i] + bsum[blockIdx.x];
        start[i] = v;
        cursor[i] = v;
    }
}

__global__ __launch_bounds__(256) void k_place(const int* __restrict__ src, const int* __restrict__ dst,
                                               int* __restrict__ cursor, int* __restrict__ srcs, int e) {
    int i = blockIdx.x * 256 + threadIdx.x;
    if (i < e) {
        int slot = atomicAdd(&cursor[dst[i]], 1);
        srcs[slot] = src[i];
    }
}

// ---------------- GEMM: W transposed in LDS, pad stride == 12 (mod 32) so the 64-lane
// ds_read_b128 is bank-conflict-free; unroll-4 (runtime k4) to cap live registers ----------------

#define FMA4W(ACC, V, WV)                 \
    ACC = fmaf((V).x, (WV).x, ACC);       \
    ACC = fmaf((V).y, (WV).y, ACC);       \
    ACC = fmaf((V).z, (WV).z, ACC);       \
    ACC = fmaf((V).w, (WV).w, ACC);

#define LSTRIDE 76    // 64 K + pad; 76 % 32 == 12 -> conflict-free, 304 B row (16B aligned)
#define PSTRIDE 140   // 128 K + pad; 140 % 32 == 12 -> conflict-free, 560 B row

// u = dinv * (h @ W)   (N x 64) @ (64 x 64)
__global__ __launch_bounds__(256, 4) void k_gemm_l(const float* __restrict__ H, const float* __restrict__ W,
                                                   const float* __restrict__ dinv, float* __restrict__ U, int n) {
    __shared__ float WT[64 * LSTRIDE];     // WT[c][k]
    for (int i = threadIdx.x; i < 64 * 64; i += 256) {
        int k = i >> 6, c = i & 63;
        WT[c * LSTRIDE + k] = W[i];        // W[k][c], coalesced read
    }
    __syncthreads();
    int lane = threadIdx.x & 63;
    const float* wl = &WT[lane * LSTRIDE];
    int gw = (blockIdx.x * 256 + threadIdx.x) >> 6;
    int nw = (gridDim.x * 256) >> 6;
    int ngrp = (n + 3) >> 2;
    for (int grp = gw; grp < ngrp; grp += nw) {
        int r0 = grp * 4;
        int r1 = min(r0 + 1, n - 1), r2 = min(r0 + 2, n - 1), r3 = min(r0 + 3, n - 1);
        const float4* h0 = (const float4*)(H + (size_t)r0 * F_DIM);
        const float4* h1 = (const float4*)(H + (size_t)r1 * F_DIM);
        const float4* h2 = (const float4*)(H + (size_t)r2 * F_DIM);
        const float4* h3 = (const float4*)(H + (size_t)r3 * F_DIM);
        float a0 = 0.f, a1 = 0.f, a2 = 0.f, a3 = 0.f;
#pragma unroll 4
        for (int k4 = 0; k4 < 16; ++k4) {
            float4 wv = *(const float4*)(wl + 4 * k4);
            float4 v0 = h0[k4], v1 = h1[k4], v2 = h2[k4], v3 = h3[k4];
            FMA4W(a0, v0, wv); FMA4W(a1, v1, wv);
            FMA4W(a2, v2, wv); FMA4W(a3, v3, wv);
        }
        U[(size_t)r0 * F_DIM + lane] = dinv[r0] * a0;
        if (r0 + 1 < n) U[(size_t)(r0 + 1) * F_DIM + lane] = dinv[r0 + 1] * a1;
        if (r0 + 2 < n) U[(size_t)(r0 + 2) * F_DIM + lane] = dinv[r0 + 2] * a2;
        if (r0 + 3 < n) U[(size_t)(r0 + 3) * F_DIM + lane] = dinv[r0 + 3] * a3;
    }
}

// h = x @ W_pre + b_pre   (N x 128) @ (128 x 64)
__global__ __launch_bounds__(256, 4) void k_gemm_pre(const float* __restrict__ X, const float* __restrict__ W,
                                                     const float* __restrict__ b, float* __restrict__ H, int n) {
    __shared__ float WT[64 * PSTRIDE];     // WT[c][k], k=0..127
    for (int i = threadIdx.x; i < 128 * 64; i += 256) {
        int k = i >> 6, c = i & 63;
        WT[c * PSTRIDE + k] = W[i];
    }
    __syncthreads();
    int lane = threadIdx.x & 63;
    float bj = b[lane];
    const float* wl = &WT[lane * PSTRIDE];
    int gw = (blockIdx.x * 256 + threadIdx.x) >> 6;
    int nw = (gridDim.x * 256) >> 6;
    int ngrp = (n + 3) >> 2;
    for (int grp = gw; grp < ngrp; grp += nw) {
        int r0 = grp * 4;
        int r1 = min(r0 + 1, n - 1), r2 = min(r0 + 2, n - 1), r3 = min(r0 + 3, n - 1);
        const float4* h0 = (const float4*)(X + (size_t)r0 * N_DIM);
        const float4* h1 = (const float4*)(X + (size_t)r1 * N_DIM);
        const float4* h2 = (const float4*)(X + (size_t)r2 * N_DIM);
        const float4* h3 = (const float4*)(X + (size_t)r3 * N_DIM);
        float a0 = bj, a1 = bj, a2 = bj, a3 = bj;
#pragma unroll 4
        for (int k4 = 0; k4 < 32; ++k4) {
            float4 wv = *(const float4*)(wl + 4 * k4);
            float4 v0 = h0[k4], v1 = h1[k4], v2 = h2[k4], v3 = h3[k4];
            FMA4W(a0, v0, wv); FMA4W(a1, v1, wv);
            FMA4W(a2, v2, wv); FMA4W(a3, v3, wv);
        }
        H[(size_t)r0 * F_DIM + lane] = a0;
        if (r0 + 1 < n) H[(size_t)(r0 + 1) * F_DIM + lane] = a1;
        if (r0 + 2 < n) H[(size_t)(r0 + 2) * F_DIM + lane] = a2;
        if (r0 + 3 < n) H[(size_t)(r0 + 3) * F_DIM + lane] = a3;
    }
}

// ---------------- aggregation: wave per node, 4x16-lane groups, direct broadcast index
// loads (no shfl), 32 edges / 8 row-loads in flight per iteration ----------------
// out[i] = epilogue( dinv[i]*(u[i] + sum_{src->i} u[src]) + b )
// MODE 0: relu -> out ; MODE 1: row L2-normalize -> out
template <int MODE>
__global__ __launch_bounds__(256) void k_agg(const float* __restrict__ U, const int* __restrict__ srcs,
                                             const int* __restrict__ start, const float* __restrict__ dinv,
                                             const float* __restrict__ bias, float* __restrict__ out, int n) {
    int node = blockIdx.x * 4 + (threadIdx.x >> 6);
    if (node >= n) return;
    int lane = threadIdx.x & 63;
    int g = lane >> 4;       // edge sub-slot 0..3
    int t = lane & 15;       // float4 column slot
    const float4* U4 = (const float4*)U;

    int s0 = start[node];
    int s1 = start[node + 1];

    float4 z = make_float4(0.f, 0.f, 0.f, 0.f);
    float4 acc = (g == 0) ? U4[(size_t)node * 16 + t] : z;   // self-loop term
    float4 acc2 = z;

    for (int p = s0; p < s1; p += 32) {
        int e0 = p + g, e1 = p + 4 + g, e2 = p + 8 + g, e3 = p + 12 + g;
        int e4 = p + 16 + g, e5 = p + 20 + g, e6 = p + 24 + g, e7 = p + 28 + g;
        // broadcast index loads (uniform within 16-lane group)
        int i0 = (e0 < s1) ? srcs[e0] : 0;
        int i1 = (e1 < s1) ? srcs[e1] : 0;
        int i2 = (e2 < s1) ? srcs[e2] : 0;
        int i3 = (e3 < s1) ? srcs[e3] : 0;
        int i4 = (e4 < s1) ? srcs[e4] : 0;
        int i5 = (e5 < s1) ? srcs[e5] : 0;
        int i6 = (e6 < s1) ? srcs[e6] : 0;
        int i7 = (e7 < s1) ? srcs[e7] : 0;
        float4 v0 = (e0 < s1) ? U4[(size_t)i0 * 16 + t] : z;
        float4 v1 = (e1 < s1) ? U4[(size_t)i1 * 16 + t] : z;
        float4 v2 = (e2 < s1) ? U4[(size_t)i2 * 16 + t] : z;
        float4 v3 = (e3 < s1) ? U4[(size_t)i3 * 16 + t] : z;
        float4 v4 = (e4 < s1) ? U4[(size_t)i4 * 16 + t] : z;
        float4 v5 = (e5 < s1) ? U4[(size_t)i5 * 16 + t] : z;
        float4 v6 = (e6 < s1) ? U4[(size_t)i6 * 16 + t] : z;
        float4 v7 = (e7 < s1) ? U4[(size_t)i7 * 16 + t] : z;
        acc.x += (v0.x + v1.x) + (v2.x + v3.x);
        acc.y += (v0.y + v1.y) + (v2.y + v3.y);
        acc.z += (v0.z + v1.z) + (v2.z + v3.z);
        acc.w += (v0.w + v1.w) + (v2.w + v3.w);
        acc2.x += (v4.x + v5.x) + (v6.x + v7.x);
        acc2.y += (v4.y + v5.y) + (v6.y + v7.y);
        acc2.z += (v4.z + v5.z) + (v6.z + v7.z);
        acc2.w += (v4.w + v5.w) + (v6.w + v7.w);
    }
    acc.x += acc2.x; acc.y += acc2.y; acc.z += acc2.z; acc.w += acc2.w;

    // reduce across the 4 sub-slots (lanes ^16, ^32)
    acc.x += __shfl_xor(acc.x, 16); acc.x += __shfl_xor(acc.x, 32);
    acc.y += __shfl_xor(acc.y, 16); acc.y += __shfl_xor(acc.y, 32);
    acc.z += __shfl_xor(acc.z, 16); acc.z += __shfl_xor(acc.z, 32);
    acc.w += __shfl_xor(acc.w, 16); acc.w += __shfl_xor(acc.w, 32);

    float di = dinv[node];
    float4 bv = ((const float4*)bias)[t];
    float4 v;
    v.x = fmaf(di, acc.x, bv.x);
    v.y = fmaf(di, acc.y, bv.y);
    v.z = fmaf(di, acc.z, bv.z);
    v.w = fmaf(di, acc.w, bv.w);

    if (MODE == 0) {
        if (g == 0) {
            float4 r;
            r.x = fmaxf(v.x, 0.f); r.y = fmaxf(v.y, 0.f);
            r.z = fmaxf(v.z, 0.f); r.w = fmaxf(v.w, 0.f);
            ((float4*)out)[(size_t)node * 16 + t] = r;
        }
    } else {
        float ss = v.x * v.x + v.y * v.y + v.z * v.z + v.w * v.w;
        ss += __shfl_xor(ss, 1);
        ss += __shfl_xor(ss, 2);
        ss += __shfl_xor(ss, 4);
        ss += __shfl_xor(ss, 8);
        float inv = 1.0f / fmaxf(sqrtf(ss), 1e-12f);
        if (g == 0) {
            float4 r;
            r.x = v.x * inv; r.y = v.y * inv; r.z = v.z * inv; r.w = v.w * inv;
            ((float4*)out)[(size_t)node * 16 + t] = r;
        }
    }
}

// ---------------- launch ----------------

extern "C" void kernel_launch(void* const* d_in, const int* in_sizes, int n_in,
                              void* d_out, int out_size, void* d_ws, size_t ws_size,
                              hipStream_t stream) {
    const float* x     = (const float*)d_in[0];
    const int*   ei    = (const int*)d_in[1];
    const float* W_pre = (const float*)d_in[2];
    const float* b_pre = (const float*)d_in[3];
    const float* W1    = (const float*)d_in[4];
    const float* b1    = (const float*)d_in[5];
    const float* Wh    = (const float*)d_in[6];
    const float* bh    = (const float*)d_in[7];
    const float* Wo    = (const float*)d_in[8];
    const float* bo    = (const float*)d_in[9];

    int n = in_sizes[0] / N_DIM;   // 100000
    int e = in_sizes[1] / 2;       // 1600000
    const int* srcIdx = ei;
    const int* dstIdx = ei + e;

    // workspace carve-out
    size_t off = 0;
    auto alloc = [&](size_t bytes) -> void* {
        void* p = (char*)d_ws + off;
        off += (bytes + 255) & ~(size_t)255;
        return p;
    };
    int*   cnt    = (int*)alloc((size_t)n * 4);
    int*   start  = (int*)alloc((size_t)(n + 1) * 4);
    int*   cursor = (int*)alloc((size_t)n * 4);
    float* dinv   = (float*)alloc((size_t)n * 4);
    int*   bsum   = (int*)alloc(512 * 4);
    int*   srcs   = (int*)alloc((size_t)e * 4);
    float* h      = (float*)alloc((size_t)n * F_DIM * 4);
    float* u      = (float*)alloc((size_t)n * F_DIM * 4);

    int nbN = (n + 255) / 256;
    int nbE = (e + 255) / 256;

    // 1. degree count (without self loops)
    hipMemsetAsync(cnt, 0, (size_t)n * 4, stream);
    k_count<<<nbE, 256, 0, stream>>>(dstIdx, cnt, e);
    k_dinv<<<nbN, 256, 0, stream>>>(cnt, dinv, n);

    // 2. exclusive scan of counts -> start offsets, cursor copy
    k_scan1<<<nbN, 256, 0, stream>>>(cnt, start, bsum, n);
    k_scan2<<<1, 512, 0, stream>>>(bsum, nbN, start, n);
    k_scan3<<<nbN, 256, 0, stream>>>(start, cursor, bsum, n);

    // 3. place src indices sorted by dst
    k_place<<<nbE, 256, 0, stream>>>(srcIdx, dstIdx, cursor, srcs, e);

    // 4. feature_pre linear: h = x @ W_pre + b_pre
    k_gemm_pre<<<2048, 256, 0, stream>>>(x, W_pre, b_pre, h, n);

    // 5. layer 1
    k_gemm_l<<<2048, 256, 0, stream>>>(h, W1, dinv, u, n);
    k_agg<0><<<(n + 3) / 4, 256, 0, stream>>>(u, srcs, start, dinv, b1, h, n);

    // 6. layer 2
    k_gemm_l<<<2048, 256, 0, stream>>>(h, Wh, dinv, u, n);
    k_agg<0><<<(n + 3) / 4, 256, 0, stream>>>(u, srcs, start, dinv, bh, h, n);

    // 7. layer 3 + final row L2 normalize -> d_out
    k_gemm_l<<<2048, 256, 0, stream>>>(h, Wo, dinv, u, n);
    k_agg<1><<<(n + 3) / 4, 256, 0, stream>>>(u, srcs, start, dinv, bo, (float*)d_out, n);
}

// Round 6
// 753.110 us; speedup vs baseline: 1.5958x; 1.0665x over previous
//
#include <hip/hip_runtime.h>

#define N_DIM 128
#define F_DIM 64
#define NXCD 8

// ---------------- degree / sort kernels ----------------

__global__ __launch_bounds__(256) void k_count(const int* __restrict__ dst, int* __restrict__ cnt, int e) {
    int i = blockIdx.x * 256 + threadIdx.x;
    if (i < e) atomicAdd(&cnt[dst[i]], 1);
}

__global__ __launch_bounds__(256) void k_dinv(const int* __restrict__ cnt, float* __restrict__ dinv, int n) {
    int i = blockIdx.x * 256 + threadIdx.x;
    if (i < n) dinv[i] = rsqrtf((float)cnt[i] + 1.0f);   // +1 self loop
}

__global__ __launch_bounds__(256) void k_scan1(const int* __restrict__ cnt, int* __restrict__ excl,
                                               int* __restrict__ bsum, int n) {
    __shared__ int s[256];
    int t = threadIdx.x;
    int i = blockIdx.x * 256 + t;
    int v = (i < n) ? cnt[i] : 0;
    s[t] = v;
    __syncthreads();
    for (int off = 1; off < 256; off <<= 1) {
        int x = (t >= off) ? s[t - off] : 0;
        __syncthreads();
        s[t] += x;
        __syncthreads();
    }
    if (i < n) excl[i] = s[t] - v;
    if (t == 255) bsum[blockIdx.x] = s[255];
}

__global__ __launch_bounds__(512) void k_scan2(int* __restrict__ bsum, int nb, int* __restrict__ start, int n) {
    __shared__ int s[512];
    int t = threadIdx.x;
    int v = (t < nb) ? bsum[t] : 0;
    s[t] = v;
    __syncthreads();
    for (int off = 1; off < 512; off <<= 1) {
        int x = (t >= off) ? s[t - off] : 0;
        __syncthreads();
        s[t] += x;
        __syncthreads();
    }
    if (t < nb) bsum[t] = s[t] - v;     // exclusive block offsets
    if (t == 511) start[n] = s[511];    // total edge count
}

__global__ __launch_bounds__(256) void k_scan3(int* __restrict__ start, int* __restrict__ cursor,
                                               const int* __restrict__ bsum, int n) {
    int i = blockIdx.x * 256 + threadIdx.x;
    if (i < n) {
        int v = start[i] + bsum[blockIdx.x];
        start[i] = v;
        cursor[i] = v;
    }
}

// Partitioned placement: blocks with blockIdx%8==p (-> XCD p) handle only dst in chunk p,
// so scatter writes to srcs stay in ONE XCD's L2 until final writeback (no 8-way line ping-pong).
__global__ __launch_bounds__(256) void k_place(const int* __restrict__ src, const int* __restrict__ dst,
                                               int* __restrict__ cursor, int* __restrict__ srcs,
                                               int e, int nchunk) {
    int p = blockIdx.x & (NXCD - 1);
    int q = blockIdx.x >> 3;
    int nq = gridDim.x >> 3;
    int lo = p * nchunk, hi = lo + nchunk;
    for (int i = q * 256 + threadIdx.x; i < e; i += nq * 256) {
        int d = dst[i];
        if (d >= lo && d < hi) {
            int slot = atomicAdd(&cursor[d], 1);
            srcs[slot] = src[i];
        }
    }
}

// ---------------- GEMM: W transposed in LDS, pad stride == 12 (mod 32) so the 64-lane
// ds_read_b128 is bank-conflict-free; unroll-4 (runtime k4) to cap live registers ----------------

#define FMA4W(ACC, V, WV)                 \
    ACC = fmaf((V).x, (WV).x, ACC);       \
    ACC = fmaf((V).y, (WV).y, ACC);       \
    ACC = fmaf((V).z, (WV).z, ACC);       \
    ACC = fmaf((V).w, (WV).w, ACC);

#define LSTRIDE 76    // 64 K + pad; 76 % 32 == 12 -> conflict-free, 304 B row (16B aligned)
#define PSTRIDE 140   // 128 K + pad; 140 % 32 == 12 -> conflict-free, 560 B row

// u = dinv * (h @ W)   (N x 64) @ (64 x 64)
__global__ __launch_bounds__(256, 4) void k_gemm_l(const float* __restrict__ H, const float* __restrict__ W,
                                                   const float* __restrict__ dinv, float* __restrict__ U, int n) {
    __shared__ float WT[64 * LSTRIDE];     // WT[c][k]
    for (int i = threadIdx.x; i < 64 * 64; i += 256) {
        int k = i >> 6, c = i & 63;
        WT[c * LSTRIDE + k] = W[i];        // W[k][c], coalesced read
    }
    __syncthreads();
    int lane = threadIdx.x & 63;
    const float* wl = &WT[lane * LSTRIDE];
    int gw = (blockIdx.x * 256 + threadIdx.x) >> 6;
    int nw = (gridDim.x * 256) >> 6;
    int ngrp = (n + 3) >> 2;
    for (int grp = gw; grp < ngrp; grp += nw) {
        int r0 = grp * 4;
        int r1 = min(r0 + 1, n - 1), r2 = min(r0 + 2, n - 1), r3 = min(r0 + 3, n - 1);
        const float4* h0 = (const float4*)(H + (size_t)r0 * F_DIM);
        const float4* h1 = (const float4*)(H + (size_t)r1 * F_DIM);
        const float4* h2 = (const float4*)(H + (size_t)r2 * F_DIM);
        const float4* h3 = (const float4*)(H + (size_t)r3 * F_DIM);
        float a0 = 0.f, a1 = 0.f, a2 = 0.f, a3 = 0.f;
#pragma unroll 4
        for (int k4 = 0; k4 < 16; ++k4) {
            float4 wv = *(const float4*)(wl + 4 * k4);
            float4 v0 = h0[k4], v1 = h1[k4], v2 = h2[k4], v3 = h3[k4];
            FMA4W(a0, v0, wv); FMA4W(a1, v1, wv);
            FMA4W(a2, v2, wv); FMA4W(a3, v3, wv);
        }
        U[(size_t)r0 * F_DIM + lane] = dinv[r0] * a0;
        if (r0 + 1 < n) U[(size_t)(r0 + 1) * F_DIM + lane] = dinv[r0 + 1] * a1;
        if (r0 + 2 < n) U[(size_t)(r0 + 2) * F_DIM + lane] = dinv[r0 + 2] * a2;
        if (r0 + 3 < n) U[(size_t)(r0 + 3) * F_DIM + lane] = dinv[r0 + 3] * a3;
    }
}

// h = x @ W_pre + b_pre   (N x 128) @ (128 x 64)
__global__ __launch_bounds__(256, 4) void k_gemm_pre(const float* __restrict__ X, const float* __restrict__ W,
                                                     const float* __restrict__ b, float* __restrict__ H, int n) {
    __shared__ float WT[64 * PSTRIDE];     // WT[c][k], k=0..127
    for (int i = threadIdx.x; i < 128 * 64; i += 256) {
        int k = i >> 6, c = i & 63;
        WT[c * PSTRIDE + k] = W[i];
    }
    __syncthreads();
    int lane = threadIdx.x & 63;
    float bj = b[lane];
    const float* wl = &WT[lane * PSTRIDE];
    int gw = (blockIdx.x * 256 + threadIdx.x) >> 6;
    int nw = (gridDim.x * 256) >> 6;
    int ngrp = (n + 3) >> 2;
    for (int grp = gw; grp < ngrp; grp += nw) {
        int r0 = grp * 4;
        int r1 = min(r0 + 1, n - 1), r2 = min(r0 + 2, n - 1), r3 = min(r0 + 3, n - 1);
        const float4* h0 = (const float4*)(X + (size_t)r0 * N_DIM);
        const float4* h1 = (const float4*)(X + (size_t)r1 * N_DIM);
        const float4* h2 = (const float4*)(X + (size_t)r2 * N_DIM);
        const float4* h3 = (const float4*)(X + (size_t)r3 * N_DIM);
        float a0 = bj, a1 = bj, a2 = bj, a3 = bj;
#pragma unroll 4
        for (int k4 = 0; k4 < 32; ++k4) {
            float4 wv = *(const float4*)(wl + 4 * k4);
            float4 v0 = h0[k4], v1 = h1[k4], v2 = h2[k4], v3 = h3[k4];
            FMA4W(a0, v0, wv); FMA4W(a1, v1, wv);
            FMA4W(a2, v2, wv); FMA4W(a3, v3, wv);
        }
        H[(size_t)r0 * F_DIM + lane] = a0;
        if (r0 + 1 < n) H[(size_t)(r0 + 1) * F_DIM + lane] = a1;
        if (r0 + 2 < n) H[(size_t)(r0 + 2) * F_DIM + lane] = a2;
        if (r0 + 3 < n) H[(size_t)(r0 + 3) * F_DIM + lane] = a3;
    }
}

// ---------------- aggregation: wave per node, 4x16-lane groups, direct broadcast index
// loads (no shfl), 32 edges / 8 row-loads in flight per iteration ----------------
// out[i] = epilogue( dinv[i]*(u[i] + sum_{src->i} u[src]) + b )
// MODE 0: relu -> out ; MODE 1: row L2-normalize -> out
template <int MODE>
__global__ __launch_bounds__(256) void k_agg(const float* __restrict__ U, const int* __restrict__ srcs,
                                             const int* __restrict__ start, const float* __restrict__ dinv,
                                             const float* __restrict__ bias, float* __restrict__ out, int n) {
    int node = blockIdx.x * 4 + (threadIdx.x >> 6);
    if (node >= n) return;
    int lane = threadIdx.x & 63;
    int g = lane >> 4;       // edge sub-slot 0..3
    int t = lane & 15;       // float4 column slot
    const float4* U4 = (const float4*)U;

    int s0 = start[node];
    int s1 = start[node + 1];

    float4 z = make_float4(0.f, 0.f, 0.f, 0.f);
    float4 acc = (g == 0) ? U4[(size_t)node * 16 + t] : z;   // self-loop term
    float4 acc2 = z;

    for (int p = s0; p < s1; p += 32) {
        int e0 = p + g, e1 = p + 4 + g, e2 = p + 8 + g, e3 = p + 12 + g;
        int e4 = p + 16 + g, e5 = p + 20 + g, e6 = p + 24 + g, e7 = p + 28 + g;
        // broadcast index loads (uniform within 16-lane group)
        int i0 = (e0 < s1) ? srcs[e0] : 0;
        int i1 = (e1 < s1) ? srcs[e1] : 0;
        int i2 = (e2 < s1) ? srcs[e2] : 0;
        int i3 = (e3 < s1) ? srcs[e3] : 0;
        int i4 = (e4 < s1) ? srcs[e4] : 0;
        int i5 = (e5 < s1) ? srcs[e5] : 0;
        int i6 = (e6 < s1) ? srcs[e6] : 0;
        int i7 = (e7 < s1) ? srcs[e7] : 0;
        float4 v0 = (e0 < s1) ? U4[(size_t)i0 * 16 + t] : z;
        float4 v1 = (e1 < s1) ? U4[(size_t)i1 * 16 + t] : z;
        float4 v2 = (e2 < s1) ? U4[(size_t)i2 * 16 + t] : z;
        float4 v3 = (e3 < s1) ? U4[(size_t)i3 * 16 + t] : z;
        float4 v4 = (e4 < s1) ? U4[(size_t)i4 * 16 + t] : z;
        float4 v5 = (e5 < s1) ? U4[(size_t)i5 * 16 + t] : z;
        float4 v6 = (e6 < s1) ? U4[(size_t)i6 * 16 + t] : z;
        float4 v7 = (e7 < s1) ? U4[(size_t)i7 * 16 + t] : z;
        acc.x += (v0.x + v1.x) + (v2.x + v3.x);
        acc.y += (v0.y + v1.y) + (v2.y + v3.y);
        acc.z += (v0.z + v1.z) + (v2.z + v3.z);
        acc.w += (v0.w + v1.w) + (v2.w + v3.w);
        acc2.x += (v4.x + v5.x) + (v6.x + v7.x);
        acc2.y += (v4.y + v5.y) + (v6.y + v7.y);
        acc2.z += (v4.z + v5.z) + (v6.z + v7.z);
        acc2.w += (v4.w + v5.w) + (v6.w + v7.w);
    }
    acc.x += acc2.x; acc.y += acc2.y; acc.z += acc2.z; acc.w += acc2.w;

    // reduce across the 4 sub-slots (lanes ^16, ^32)
    acc.x += __shfl_xor(acc.x, 16); acc.x += __shfl_xor(acc.x, 32);
    acc.y += __shfl_xor(acc.y, 16); acc.y += __shfl_xor(acc.y, 32);
    acc.z += __shfl_xor(acc.z, 16); acc.z += __shfl_xor(acc.z, 32);
    acc.w += __shfl_xor(acc.w, 16); acc.w += __shfl_xor(acc.w, 32);

    float di = dinv[node];
    float4 bv = ((const float4*)bias)[t];
    float4 v;
    v.x = fmaf(di, acc.x, bv.x);
    v.y = fmaf(di, acc.y, bv.y);
    v.z = fmaf(di, acc.z, bv.z);
    v.w = fmaf(di, acc.w, bv.w);

    if (MODE == 0) {
        if (g == 0) {
            float4 r;
            r.x = fmaxf(v.x, 0.f); r.y = fmaxf(v.y, 0.f);
            r.z = fmaxf(v.z, 0.f); r.w = fmaxf(v.w, 0.f);
            ((float4*)out)[(size_t)node * 16 + t] = r;
        }
    } else {
        float ss = v.x * v.x + v.y * v.y + v.z * v.z + v.w * v.w;
        ss += __shfl_xor(ss, 1);
        ss += __shfl_xor(ss, 2);
        ss += __shfl_xor(ss, 4);
        ss += __shfl_xor(ss, 8);
        float inv = 1.0f / fmaxf(sqrtf(ss), 1e-12f);
        if (g == 0) {
            float4 r;
            r.x = v.x * inv; r.y = v.y * inv; r.z = v.z * inv; r.w = v.w * inv;
            ((float4*)out)[(size_t)node * 16 + t] = r;
        }
    }
}

// ---------------- launch ----------------

extern "C" void kernel_launch(void* const* d_in, const int* in_sizes, int n_in,
                              void* d_out, int out_size, void* d_ws, size_t ws_size,
                              hipStream_t stream) {
    const float* x     = (const float*)d_in[0];
    const int*   ei    = (const int*)d_in[1];
    const float* W_pre = (const float*)d_in[2];
    const float* b_pre = (const float*)d_in[3];
    const float* W1    = (const float*)d_in[4];
    const float* b1    = (const float*)d_in[5];
    const float* Wh    = (const float*)d_in[6];
    const float* bh    = (const float*)d_in[7];
    const float* Wo    = (const float*)d_in[8];
    const float* bo    = (const float*)d_in[9];

    int n = in_sizes[0] / N_DIM;   // 100000
    int e = in_sizes[1] / 2;       // 1600000
    const int* srcIdx = ei;
    const int* dstIdx = ei + e;

    // workspace carve-out
    size_t off = 0;
    auto alloc = [&](size_t bytes) -> void* {
        void* p = (char*)d_ws + off;
        off += (bytes + 255) & ~(size_t)255;
        return p;
    };
    int*   cnt    = (int*)alloc((size_t)n * 4);
    int*   start  = (int*)alloc((size_t)(n + 1) * 4);
    int*   cursor = (int*)alloc((size_t)n * 4);
    float* dinv   = (float*)alloc((size_t)n * 4);
    int*   bsum   = (int*)alloc(512 * 4);
    int*   srcs   = (int*)alloc((size_t)e * 4);
    float* h      = (float*)alloc((size_t)n * F_DIM * 4);
    float* u      = (float*)alloc((size_t)n * F_DIM * 4);

    int nbN = (n + 255) / 256;
    int nbE = (e + 255) / 256;

    // 1. degree count (without self loops)
    hipMemsetAsync(cnt, 0, (size_t)n * 4, stream);
    k_count<<<nbE, 256, 0, stream>>>(dstIdx, cnt, e);
    k_dinv<<<nbN, 256, 0, stream>>>(cnt, dinv, n);

    // 2. exclusive scan of counts -> start offsets, cursor copy
    k_scan1<<<nbN, 256, 0, stream>>>(cnt, start, bsum, n);
    k_scan2<<<1, 512, 0, stream>>>(bsum, nbN, start, n);
    k_scan3<<<nbN, 256, 0, stream>>>(start, cursor, bsum, n);

    // 3. place src indices sorted by dst (XCD-partitioned scatter)
    int nchunk = (n + NXCD - 1) / NXCD;
    k_place<<<2048, 256, 0, stream>>>(srcIdx, dstIdx, cursor, srcs, e, nchunk);

    // 4. feature_pre linear: h = x @ W_pre + b_pre
    k_gemm_pre<<<2048, 256, 0, stream>>>(x, W_pre, b_pre, h, n);

    // 5. layer 1
    k_gemm_l<<<2048, 256, 0, stream>>>(h, W1, dinv, u, n);
    k_agg<0><<<(n + 3) / 4, 256, 0, stream>>>(u, srcs, start, dinv, b1, h, n);

    // 6. layer 2
    k_gemm_l<<<2048, 256, 0, stream>>>(h, Wh, dinv, u, n);
    k_agg<0><<<(n + 3) / 4, 256, 0, stream>>>(u, srcs, start, dinv, bh, h, n);

    // 7. layer 3 + final row L2 normalize -> d_out
    k_gemm_l<<<2048, 256, 0, stream>>>(h, Wo, dinv, u, n);
    k_agg<1><<<(n + 3) / 4, 256, 0, stream>>>(u, srcs, start, dinv, bo, (float*)d_out, n);
}

// Round 7
// 605.070 us; speedup vs baseline: 1.9862x; 1.2447x over previous
//
#include <hip/hip_runtime.h>
#include <hip/hip_fp16.h>

#define N_DIM 128
#define F_DIM 64
#define NXCD 8

// ---------------- degree / sort kernels ----------------

// XCD-partitioned count: blocks with blockIdx%8==p handle only dst in chunk p, so each
// cnt[] cache line is atomically updated by ONE XCD's L2 (no cross-XCD line ping-pong).
__global__ __launch_bounds__(256) void k_count(const int* __restrict__ dst, int* __restrict__ cnt,
                                               int e, int nchunk) {
    int p = blockIdx.x & (NXCD - 1);
    int q = blockIdx.x >> 3;
    int nq = gridDim.x >> 3;
    int lo = p * nchunk, hi = lo + nchunk;
    for (int i = q * 256 + threadIdx.x; i < e; i += nq * 256) {
        int d = dst[i];
        if (d >= lo && d < hi) atomicAdd(&cnt[d], 1);
    }
}

__global__ __launch_bounds__(256) void k_dinv(const int* __restrict__ cnt, float* __restrict__ dinv, int n) {
    int i = blockIdx.x * 256 + threadIdx.x;
    if (i < n) dinv[i] = rsqrtf((float)cnt[i] + 1.0f);   // +1 self loop
}

__global__ __launch_bounds__(256) void k_scan1(const int* __restrict__ cnt, int* __restrict__ excl,
                                               int* __restrict__ bsum, int n) {
    __shared__ int s[256];
    int t = threadIdx.x;
    int i = blockIdx.x * 256 + t;
    int v = (i < n) ? cnt[i] : 0;
    s[t] = v;
    __syncthreads();
    for (int off = 1; off < 256; off <<= 1) {
        int x = (t >= off) ? s[t - off] : 0;
        __syncthreads();
        s[t] += x;
        __syncthreads();
    }
    if (i < n) excl[i] = s[t] - v;
    if (t == 255) bsum[blockIdx.x] = s[255];
}

__global__ __launch_bounds__(512) void k_scan2(int* __restrict__ bsum, int nb, int* __restrict__ start, int n) {
    __shared__ int s[512];
    int t = threadIdx.x;
    int v = (t < nb) ? bsum[t] : 0;
    s[t] = v;
    __syncthreads();
    for (int off = 1; off < 512; off <<= 1) {
        int x = (t >= off) ? s[t - off] : 0;
        __syncthreads();
        s[t] += x;
        __syncthreads();
    }
    if (t < nb) bsum[t] = s[t] - v;     // exclusive block offsets
    if (t == 511) start[n] = s[511];    // total edge count
}

__global__ __launch_bounds__(256) void k_scan3(int* __restrict__ start, int* __restrict__ cursor,
                                               const int* __restrict__ bsum, int n) {
    int i = blockIdx.x * 256 + threadIdx.x;
    if (i < n) {
        int v = start[i] + bsum[blockIdx.x];
        start[i] = v;
        cursor[i] = v;
    }
}

// XCD-partitioned placement (same mechanism as k_count; srcs lines stay in one L2).
__global__ __launch_bounds__(256) void k_place(const int* __restrict__ src, const int* __restrict__ dst,
                                               int* __restrict__ cursor, int* __restrict__ srcs,
                                               int e, int nchunk) {
    int p = blockIdx.x & (NXCD - 1);
    int q = blockIdx.x >> 3;
    int nq = gridDim.x >> 3;
    int lo = p * nchunk, hi = lo + nchunk;
    for (int i = q * 256 + threadIdx.x; i < e; i += nq * 256) {
        int d = dst[i];
        if (d >= lo && d < hi) {
            int slot = atomicAdd(&cursor[d], 1);
            srcs[slot] = src[i];
        }
    }
}

// ---------------- GEMM: W row-major in LDS, scalar ds_read_b32 per weight
// (lane-indexed -> consecutive dwords -> conflict-free); h rows via wave-uniform
// broadcast float4 loads; 4 rows per wave ----------------

// u = dinv * (h @ W)   (N x 64) @ (64 x 64), fp16 output
__global__ __launch_bounds__(256, 4) void k_gemm_l(const float* __restrict__ H, const float* __restrict__ W,
                                                   const float* __restrict__ dinv, __half* __restrict__ U, int n) {
    __shared__ float Wl[64 * 64];
    for (int i = threadIdx.x; i < 64 * 64; i += 256) Wl[i] = W[i];
    __syncthreads();
    int lane = threadIdx.x & 63;
    int gw = (blockIdx.x * 256 + threadIdx.x) >> 6;
    int nw = (gridDim.x * 256) >> 6;
    int ngrp = (n + 3) >> 2;
    for (int grp = gw; grp < ngrp; grp += nw) {
        int r0 = grp * 4;
        int r1 = min(r0 + 1, n - 1), r2 = min(r0 + 2, n - 1), r3 = min(r0 + 3, n - 1);
        const float4* h0 = (const float4*)(H + (size_t)r0 * F_DIM);
        const float4* h1 = (const float4*)(H + (size_t)r1 * F_DIM);
        const float4* h2 = (const float4*)(H + (size_t)r2 * F_DIM);
        const float4* h3 = (const float4*)(H + (size_t)r3 * F_DIM);
        float a0 = 0.f, a1 = 0.f, a2 = 0.f, a3 = 0.f;
#pragma unroll 4
        for (int k4 = 0; k4 < 16; ++k4) {
            float4 v0 = h0[k4], v1 = h1[k4], v2 = h2[k4], v3 = h3[k4];
            float w0 = Wl[(4 * k4 + 0) * 64 + lane];
            float w1 = Wl[(4 * k4 + 1) * 64 + lane];
            float w2 = Wl[(4 * k4 + 2) * 64 + lane];
            float w3 = Wl[(4 * k4 + 3) * 64 + lane];
            a0 = fmaf(v0.x, w0, a0); a0 = fmaf(v0.y, w1, a0); a0 = fmaf(v0.z, w2, a0); a0 = fmaf(v0.w, w3, a0);
            a1 = fmaf(v1.x, w0, a1); a1 = fmaf(v1.y, w1, a1); a1 = fmaf(v1.z, w2, a1); a1 = fmaf(v1.w, w3, a1);
            a2 = fmaf(v2.x, w0, a2); a2 = fmaf(v2.y, w1, a2); a2 = fmaf(v2.z, w2, a2); a2 = fmaf(v2.w, w3, a2);
            a3 = fmaf(v3.x, w0, a3); a3 = fmaf(v3.y, w1, a3); a3 = fmaf(v3.z, w2, a3); a3 = fmaf(v3.w, w3, a3);
        }
        U[(size_t)r0 * F_DIM + lane] = __float2half(dinv[r0] * a0);
        if (r0 + 1 < n) U[(size_t)(r0 + 1) * F_DIM + lane] = __float2half(dinv[r0 + 1] * a1);
        if (r0 + 2 < n) U[(size_t)(r0 + 2) * F_DIM + lane] = __float2half(dinv[r0 + 2] * a2);
        if (r0 + 3 < n) U[(size_t)(r0 + 3) * F_DIM + lane] = __float2half(dinv[r0 + 3] * a3);
    }
}

// h = x @ W_pre + b_pre   (N x 128) @ (128 x 64), f32 output
__global__ __launch_bounds__(256, 4) void k_gemm_pre(const float* __restrict__ X, const float* __restrict__ W,
                                                     const float* __restrict__ b, float* __restrict__ H, int n) {
    __shared__ float Wl[128 * 64];
    for (int i = threadIdx.x; i < 128 * 64; i += 256) Wl[i] = W[i];
    __syncthreads();
    int lane = threadIdx.x & 63;
    float bj = b[lane];
    int gw = (blockIdx.x * 256 + threadIdx.x) >> 6;
    int nw = (gridDim.x * 256) >> 6;
    int ngrp = (n + 3) >> 2;
    for (int grp = gw; grp < ngrp; grp += nw) {
        int r0 = grp * 4;
        int r1 = min(r0 + 1, n - 1), r2 = min(r0 + 2, n - 1), r3 = min(r0 + 3, n - 1);
        const float4* h0 = (const float4*)(X + (size_t)r0 * N_DIM);
        const float4* h1 = (const float4*)(X + (size_t)r1 * N_DIM);
        const float4* h2 = (const float4*)(X + (size_t)r2 * N_DIM);
        const float4* h3 = (const float4*)(X + (size_t)r3 * N_DIM);
        float a0 = bj, a1 = bj, a2 = bj, a3 = bj;
#pragma unroll 4
        for (int k4 = 0; k4 < 32; ++k4) {
            float4 v0 = h0[k4], v1 = h1[k4], v2 = h2[k4], v3 = h3[k4];
            float w0 = Wl[(4 * k4 + 0) * 64 + lane];
            float w1 = Wl[(4 * k4 + 1) * 64 + lane];
            float w2 = Wl[(4 * k4 + 2) * 64 + lane];
            float w3 = Wl[(4 * k4 + 3) * 64 + lane];
            a0 = fmaf(v0.x, w0, a0); a0 = fmaf(v0.y, w1, a0); a0 = fmaf(v0.z, w2, a0); a0 = fmaf(v0.w, w3, a0);
            a1 = fmaf(v1.x, w0, a1); a1 = fmaf(v1.y, w1, a1); a1 = fmaf(v1.z, w2, a1); a1 = fmaf(v1.w, w3, a1);
            a2 = fmaf(v2.x, w0, a2); a2 = fmaf(v2.y, w1, a2); a2 = fmaf(v2.z, w2, a2); a2 = fmaf(v2.w, w3, a2);
            a3 = fmaf(v3.x, w0, a3); a3 = fmaf(v3.y, w1, a3); a3 = fmaf(v3.z, w2, a3); a3 = fmaf(v3.w, w3, a3);
        }
        H[(size_t)r0 * F_DIM + lane] = a0;
        if (r0 + 1 < n) H[(size_t)(r0 + 1) * F_DIM + lane] = a1;
        if (r0 + 2 < n) H[(size_t)(r0 + 2) * F_DIM + lane] = a2;
        if (r0 + 3 < n) H[(size_t)(r0 + 3) * F_DIM + lane] = a3;
    }
}

// ---------------- aggregation: fp16 gather payload (128 B/row), wave per node,
// 8x8-lane groups (8 lanes x 16 B = one row), 4 edges/group in flight ----------------
// out[i] = epilogue( dinv[i]*(u[i] + sum_{src->i} u[src]) + b ), f32 accumulate
// MODE 0: relu -> out(f32 h) ; MODE 1: row L2-normalize -> out(d_out)

#define ADD8(ACC, V)                                              \
    {                                                             \
        const __half2* _hp = (const __half2*)&(V);                \
        float2 _f0 = __half22float2(_hp[0]);                      \
        float2 _f1 = __half22float2(_hp[1]);                      \
        float2 _f2 = __half22float2(_hp[2]);                      \
        float2 _f3 = __half22float2(_hp[3]);                      \
        ACC[0] += _f0.x; ACC[1] += _f0.y;                         \
        ACC[2] += _f1.x; ACC[3] += _f1.y;                         \
        ACC[4] += _f2.x; ACC[5] += _f2.y;                         \
        ACC[6] += _f3.x; ACC[7] += _f3.y;                         \
    }

template <int MODE>
__global__ __launch_bounds__(256) void k_agg(const __half* __restrict__ U, const int* __restrict__ srcs,
                                             const int* __restrict__ start, const float* __restrict__ dinv,
                                             const float* __restrict__ bias, float* __restrict__ out, int n) {
    int node = blockIdx.x * 4 + (threadIdx.x >> 6);
    if (node >= n) return;
    int lane = threadIdx.x & 63;
    int g = lane >> 3;       // edge sub-slot 0..7
    int t = lane & 7;        // 16B column slot within 128B row
    const float4* U4 = (const float4*)U;

    int s0 = start[node];
    int s1 = start[node + 1];

    float acc[8];
#pragma unroll
    for (int j = 0; j < 8; ++j) acc[j] = 0.f;
    if (g == 0) {                       // self-loop term
        float4 sv = U4[(size_t)node * 8 + t];
        ADD8(acc, sv);
    }

    float4 z = make_float4(0.f, 0.f, 0.f, 0.f);
    for (int p = s0; p < s1; p += 32) {
        int e0 = p + g, e1 = p + 8 + g, e2 = p + 16 + g, e3 = p + 24 + g;
        // broadcast index loads (uniform within 8-lane group)
        int i0 = (e0 < s1) ? srcs[e0] : 0;
        int i1 = (e1 < s1) ? srcs[e1] : 0;
        int i2 = (e2 < s1) ? srcs[e2] : 0;
        int i3 = (e3 < s1) ? srcs[e3] : 0;
        float4 v0 = (e0 < s1) ? U4[(size_t)i0 * 8 + t] : z;
        float4 v1 = (e1 < s1) ? U4[(size_t)i1 * 8 + t] : z;
        float4 v2 = (e2 < s1) ? U4[(size_t)i2 * 8 + t] : z;
        float4 v3 = (e3 < s1) ? U4[(size_t)i3 * 8 + t] : z;
        ADD8(acc, v0);
        ADD8(acc, v1);
        ADD8(acc, v2);
        ADD8(acc, v3);
    }

    // reduce across the 8 sub-slots (lanes ^8, ^16, ^32)
#pragma unroll
    for (int j = 0; j < 8; ++j) {
        acc[j] += __shfl_xor(acc[j], 8);
        acc[j] += __shfl_xor(acc[j], 16);
        acc[j] += __shfl_xor(acc[j], 32);
    }

    float di = dinv[node];
    const float4* b4 = (const float4*)bias;
    float4 bv0 = b4[2 * t], bv1 = b4[2 * t + 1];
    float v[8];
    v[0] = fmaf(di, acc[0], bv0.x); v[1] = fmaf(di, acc[1], bv0.y);
    v[2] = fmaf(di, acc[2], bv0.z); v[3] = fmaf(di, acc[3], bv0.w);
    v[4] = fmaf(di, acc[4], bv1.x); v[5] = fmaf(di, acc[5], bv1.y);
    v[6] = fmaf(di, acc[6], bv1.z); v[7] = fmaf(di, acc[7], bv1.w);

    if (MODE == 0) {
        if (g == 0) {
            float4 r0, r1;
            r0.x = fmaxf(v[0], 0.f); r0.y = fmaxf(v[1], 0.f);
            r0.z = fmaxf(v[2], 0.f); r0.w = fmaxf(v[3], 0.f);
            r1.x = fmaxf(v[4], 0.f); r1.y = fmaxf(v[5], 0.f);
            r1.z = fmaxf(v[6], 0.f); r1.w = fmaxf(v[7], 0.f);
            float4* o4 = (float4*)(out + (size_t)node * F_DIM);
            o4[2 * t] = r0; o4[2 * t + 1] = r1;
        }
    } else {
        float ss = 0.f;
#pragma unroll
        for (int j = 0; j < 8; ++j) ss = fmaf(v[j], v[j], ss);
        ss += __shfl_xor(ss, 1);
        ss += __shfl_xor(ss, 2);
        ss += __shfl_xor(ss, 4);
        float inv = 1.0f / fmaxf(sqrtf(ss), 1e-12f);
        if (g == 0) {
            float4 r0, r1;
            r0.x = v[0] * inv; r0.y = v[1] * inv; r0.z = v[2] * inv; r0.w = v[3] * inv;
            r1.x = v[4] * inv; r1.y = v[5] * inv; r1.z = v[6] * inv; r1.w = v[7] * inv;
            float4* o4 = (float4*)(out + (size_t)node * F_DIM);
            o4[2 * t] = r0; o4[2 * t + 1] = r1;
        }
    }
}

// ---------------- launch ----------------

extern "C" void kernel_launch(void* const* d_in, const int* in_sizes, int n_in,
                              void* d_out, int out_size, void* d_ws, size_t ws_size,
                              hipStream_t stream) {
    const float* x     = (const float*)d_in[0];
    const int*   ei    = (const int*)d_in[1];
    const float* W_pre = (const float*)d_in[2];
    const float* b_pre = (const float*)d_in[3];
    const float* W1    = (const float*)d_in[4];
    const float* b1    = (const float*)d_in[5];
    const float* Wh    = (const float*)d_in[6];
    const float* bh    = (const float*)d_in[7];
    const float* Wo    = (const float*)d_in[8];
    const float* bo    = (const float*)d_in[9];

    int n = in_sizes[0] / N_DIM;   // 100000
    int e = in_sizes[1] / 2;       // 1600000
    const int* srcIdx = ei;
    const int* dstIdx = ei + e;

    // workspace carve-out
    size_t off = 0;
    auto alloc = [&](size_t bytes) -> void* {
        void* p = (char*)d_ws + off;
        off += (bytes + 255) & ~(size_t)255;
        return p;
    };
    int*    cnt    = (int*)alloc((size_t)n * 4);
    int*    start  = (int*)alloc((size_t)(n + 1) * 4);
    int*    cursor = (int*)alloc((size_t)n * 4);
    float*  dinv   = (float*)alloc((size_t)n * 4);
    int*    bsum   = (int*)alloc(512 * 4);
    int*    srcs   = (int*)alloc((size_t)e * 4);
    float*  h      = (float*)alloc((size_t)n * F_DIM * 4);
    __half* u      = (__half*)alloc((size_t)n * F_DIM * 2);

    int nbN = (n + 255) / 256;
    int nbE = (e + 255) / 256;
    int nchunk = (n + NXCD - 1) / NXCD;

    // 1. degree count (without self loops), XCD-partitioned
    hipMemsetAsync(cnt, 0, (size_t)n * 4, stream);
    k_count<<<2048, 256, 0, stream>>>(dstIdx, cnt, e, nchunk);
    k_dinv<<<nbN, 256, 0, stream>>>(cnt, dinv, n);

    // 2. exclusive scan of counts -> start offsets, cursor copy
    k_scan1<<<nbN, 256, 0, stream>>>(cnt, start, bsum, n);
    k_scan2<<<1, 512, 0, stream>>>(bsum, nbN, start, n);
    k_scan3<<<nbN, 256, 0, stream>>>(start, cursor, bsum, n);

    // 3. place src indices sorted by dst (XCD-partitioned scatter)
    k_place<<<2048, 256, 0, stream>>>(srcIdx, dstIdx, cursor, srcs, e, nchunk);

    // 4. feature_pre linear: h = x @ W_pre + b_pre
    k_gemm_pre<<<2048, 256, 0, stream>>>(x, W_pre, b_pre, h, n);

    // 5. layer 1
    k_gemm_l<<<2048, 256, 0, stream>>>(h, W1, dinv, u, n);
    k_agg<0><<<(n + 3) / 4, 256, 0, stream>>>(u, srcs, start, dinv, b1, h, n);

    // 6. layer 2
    k_gemm_l<<<2048, 256, 0, stream>>>(h, Wh, dinv, u, n);
    k_agg<0><<<(n + 3) / 4, 256, 0, stream>>>(u, srcs, start, dinv, bh, h, n);

    // 7. layer 3 + final row L2 normalize -> d_out
    k_gemm_l<<<2048, 256, 0, stream>>>(h, Wo, dinv, u, n);
    k_agg<1><<<(n + 3) / 4, 256, 0, stream>>>(u, srcs, start, dinv, bo, (float*)d_out, n);
}

// Round 8
// 590.299 us; speedup vs baseline: 2.0359x; 1.0250x over previous
//
#include <hip/hip_runtime.h>
#include <hip/hip_fp16.h>

#define N_DIM 128
#define F_DIM 64
#define NXCD 8

// ---------------- weight composition: Wc = W_pre @ W1 (128x64), bb = b_pre @ W1 ----------------
__global__ __launch_bounds__(256) void k_compose(const float* __restrict__ Wpre, const float* __restrict__ W1,
                                                 const float* __restrict__ bpre, float* __restrict__ Wc,
                                                 float* __restrict__ bb) {
    int c = threadIdx.x & 63;
    int rq = threadIdx.x >> 6;                 // 0..3
    for (int r = rq; r < N_DIM; r += 4) {
        float acc = 0.f;
        for (int k = 0; k < 64; ++k) acc = fmaf(Wpre[r * 64 + k], W1[k * 64 + c], acc);
        Wc[r * 64 + c] = acc;
    }
    if (rq == 0) {
        float acc = 0.f;
        for (int k = 0; k < 64; ++k) acc = fmaf(bpre[k], W1[k * 64 + c], acc);
        bb[c] = acc;
    }
}

// ---------------- degree / sort kernels ----------------

// XCD-partitioned count (cnt lines stay in one XCD's L2)
__global__ __launch_bounds__(256) void k_count(const int* __restrict__ dst, int* __restrict__ cnt,
                                               int e, int nchunk) {
    int p = blockIdx.x & (NXCD - 1);
    int q = blockIdx.x >> 3;
    int nq = gridDim.x >> 3;
    int lo = p * nchunk, hi = lo + nchunk;
    for (int i = q * 256 + threadIdx.x; i < e; i += nq * 256) {
        int d = dst[i];
        if (d >= lo && d < hi) atomicAdd(&cnt[d], 1);
    }
}

__global__ __launch_bounds__(256) void k_dinv(const int* __restrict__ cnt, float* __restrict__ dinv, int n) {
    int i = blockIdx.x * 256 + threadIdx.x;
    if (i < n) dinv[i] = rsqrtf((float)cnt[i] + 1.0f);   // +1 self loop
}

__global__ __launch_bounds__(256) void k_scan1(const int* __restrict__ cnt, int* __restrict__ excl,
                                               int* __restrict__ bsum, int n) {
    __shared__ int s[256];
    int t = threadIdx.x;
    int i = blockIdx.x * 256 + t;
    int v = (i < n) ? cnt[i] : 0;
    s[t] = v;
    __syncthreads();
    for (int off = 1; off < 256; off <<= 1) {
        int x = (t >= off) ? s[t - off] : 0;
        __syncthreads();
        s[t] += x;
        __syncthreads();
    }
    if (i < n) excl[i] = s[t] - v;
    if (t == 255) bsum[blockIdx.x] = s[255];
}

__global__ __launch_bounds__(512) void k_scan2(int* __restrict__ bsum, int nb, int* __restrict__ start, int n) {
    __shared__ int s[512];
    int t = threadIdx.x;
    int v = (t < nb) ? bsum[t] : 0;
    s[t] = v;
    __syncthreads();
    for (int off = 1; off < 512; off <<= 1) {
        int x = (t >= off) ? s[t - off] : 0;
        __syncthreads();
        s[t] += x;
        __syncthreads();
    }
    if (t < nb) bsum[t] = s[t] - v;     // exclusive block offsets
    if (t == 511) start[n] = s[511];    // total edge count
}

__global__ __launch_bounds__(256) void k_scan3(int* __restrict__ start, int* __restrict__ cursor,
                                               const int* __restrict__ bsum, int n) {
    int i = blockIdx.x * 256 + threadIdx.x;
    if (i < n) {
        int v = start[i] + bsum[blockIdx.x];
        start[i] = v;
        cursor[i] = v;
    }
}

// XCD-partitioned placement (srcs lines stay in one L2)
__global__ __launch_bounds__(256) void k_place(const int* __restrict__ src, const int* __restrict__ dst,
                                               int* __restrict__ cursor, int* __restrict__ srcs,
                                               int e, int nchunk) {
    int p = blockIdx.x & (NXCD - 1);
    int q = blockIdx.x >> 3;
    int nq = gridDim.x >> 3;
    int lo = p * nchunk, hi = lo + nchunk;
    for (int i = q * 256 + threadIdx.x; i < e; i += nq * 256) {
        int d = dst[i];
        if (d >= lo && d < hi) {
            int slot = atomicAdd(&cursor[d], 1);
            srcs[slot] = src[i];
        }
    }
}

// ---------------- GEMMs: W row-major in LDS (ds_read_b32, conflict-free), 8 rows/wave,
// ONE base pointer per row-group (all row loads via immediate offsets) ----------------

// u = dinv * (x @ Wc + bb)    (N x 128) @ (128 x 64), fp16 output  [layer-1 fused]
__global__ __launch_bounds__(256, 4) void k_gemm_f(const float* __restrict__ X, const float* __restrict__ Wc,
                                                   const float* __restrict__ bb, const float* __restrict__ dinv,
                                                   __half* __restrict__ U, int n) {
    __shared__ float Wl[N_DIM * 64];
    for (int i = threadIdx.x; i < N_DIM * 64; i += 256) Wl[i] = Wc[i];
    __syncthreads();
    int lane = threadIdx.x & 63;
    float bj = bb[lane];
    int gw = (blockIdx.x * 256 + threadIdx.x) >> 6;
    int nw = (gridDim.x * 256) >> 6;
    int ngrp = n >> 3;                              // n multiple of 8 (100000)
    for (int grp = gw; grp < ngrp; grp += nw) {
        int r0 = grp * 8;
        const float4* base = (const float4*)(X + (size_t)r0 * N_DIM);   // row j at base[j*32 + k4]
        float a0 = bj, a1 = bj, a2 = bj, a3 = bj, a4 = bj, a5 = bj, a6 = bj, a7 = bj;
#pragma unroll 2
        for (int k4 = 0; k4 < 32; ++k4) {
            float w0 = Wl[(4 * k4 + 0) * 64 + lane];
            float w1 = Wl[(4 * k4 + 1) * 64 + lane];
            float w2 = Wl[(4 * k4 + 2) * 64 + lane];
            float w3 = Wl[(4 * k4 + 3) * 64 + lane];
            float4 v;
            v = base[0 * 32 + k4]; a0 = fmaf(v.x, w0, a0); a0 = fmaf(v.y, w1, a0); a0 = fmaf(v.z, w2, a0); a0 = fmaf(v.w, w3, a0);
            v = base[1 * 32 + k4]; a1 = fmaf(v.x, w0, a1); a1 = fmaf(v.y, w1, a1); a1 = fmaf(v.z, w2, a1); a1 = fmaf(v.w, w3, a1);
            v = base[2 * 32 + k4]; a2 = fmaf(v.x, w0, a2); a2 = fmaf(v.y, w1, a2); a2 = fmaf(v.z, w2, a2); a2 = fmaf(v.w, w3, a2);
            v = base[3 * 32 + k4]; a3 = fmaf(v.x, w0, a3); a3 = fmaf(v.y, w1, a3); a3 = fmaf(v.z, w2, a3); a3 = fmaf(v.w, w3, a3);
            v = base[4 * 32 + k4]; a4 = fmaf(v.x, w0, a4); a4 = fmaf(v.y, w1, a4); a4 = fmaf(v.z, w2, a4); a4 = fmaf(v.w, w3, a4);
            v = base[5 * 32 + k4]; a5 = fmaf(v.x, w0, a5); a5 = fmaf(v.y, w1, a5); a5 = fmaf(v.z, w2, a5); a5 = fmaf(v.w, w3, a5);
            v = base[6 * 32 + k4]; a6 = fmaf(v.x, w0, a6); a6 = fmaf(v.y, w1, a6); a6 = fmaf(v.z, w2, a6); a6 = fmaf(v.w, w3, a6);
            v = base[7 * 32 + k4]; a7 = fmaf(v.x, w0, a7); a7 = fmaf(v.y, w1, a7); a7 = fmaf(v.z, w2, a7); a7 = fmaf(v.w, w3, a7);
        }
        __half* up = U + (size_t)r0 * F_DIM + lane;
        up[0 * F_DIM] = __float2half(dinv[r0 + 0] * a0);
        up[1 * F_DIM] = __float2half(dinv[r0 + 1] * a1);
        up[2 * F_DIM] = __float2half(dinv[r0 + 2] * a2);
        up[3 * F_DIM] = __float2half(dinv[r0 + 3] * a3);
        up[4 * F_DIM] = __float2half(dinv[r0 + 4] * a4);
        up[5 * F_DIM] = __float2half(dinv[r0 + 5] * a5);
        up[6 * F_DIM] = __float2half(dinv[r0 + 6] * a6);
        up[7 * F_DIM] = __float2half(dinv[r0 + 7] * a7);
    }
}

// u = dinv * (h @ W)    (N x 64) @ (64 x 64), fp16 output
__global__ __launch_bounds__(256, 4) void k_gemm_l(const float* __restrict__ H, const float* __restrict__ W,
                                                   const float* __restrict__ dinv, __half* __restrict__ U, int n) {
    __shared__ float Wl[64 * 64];
    for (int i = threadIdx.x; i < 64 * 64; i += 256) Wl[i] = W[i];
    __syncthreads();
    int lane = threadIdx.x & 63;
    int gw = (blockIdx.x * 256 + threadIdx.x) >> 6;
    int nw = (gridDim.x * 256) >> 6;
    int ngrp = n >> 3;
    for (int grp = gw; grp < ngrp; grp += nw) {
        int r0 = grp * 8;
        const float4* base = (const float4*)(H + (size_t)r0 * F_DIM);   // row j at base[j*16 + k4]
        float a0 = 0.f, a1 = 0.f, a2 = 0.f, a3 = 0.f, a4 = 0.f, a5 = 0.f, a6 = 0.f, a7 = 0.f;
#pragma unroll 2
        for (int k4 = 0; k4 < 16; ++k4) {
            float w0 = Wl[(4 * k4 + 0) * 64 + lane];
            float w1 = Wl[(4 * k4 + 1) * 64 + lane];
            float w2 = Wl[(4 * k4 + 2) * 64 + lane];
            float w3 = Wl[(4 * k4 + 3) * 64 + lane];
            float4 v;
            v = base[0 * 16 + k4]; a0 = fmaf(v.x, w0, a0); a0 = fmaf(v.y, w1, a0); a0 = fmaf(v.z, w2, a0); a0 = fmaf(v.w, w3, a0);
            v = base[1 * 16 + k4]; a1 = fmaf(v.x, w0, a1); a1 = fmaf(v.y, w1, a1); a1 = fmaf(v.z, w2, a1); a1 = fmaf(v.w, w3, a1);
            v = base[2 * 16 + k4]; a2 = fmaf(v.x, w0, a2); a2 = fmaf(v.y, w1, a2); a2 = fmaf(v.z, w2, a2); a2 = fmaf(v.w, w3, a2);
            v = base[3 * 16 + k4]; a3 = fmaf(v.x, w0, a3); a3 = fmaf(v.y, w1, a3); a3 = fmaf(v.z, w2, a3); a3 = fmaf(v.w, w3, a3);
            v = base[4 * 16 + k4]; a4 = fmaf(v.x, w0, a4); a4 = fmaf(v.y, w1, a4); a4 = fmaf(v.z, w2, a4); a4 = fmaf(v.w, w3, a4);
            v = base[5 * 16 + k4]; a5 = fmaf(v.x, w0, a5); a5 = fmaf(v.y, w1, a5); a5 = fmaf(v.z, w2, a5); a5 = fmaf(v.w, w3, a5);
            v = base[6 * 16 + k4]; a6 = fmaf(v.x, w0, a6); a6 = fmaf(v.y, w1, a6); a6 = fmaf(v.z, w2, a6); a6 = fmaf(v.w, w3, a6);
            v = base[7 * 16 + k4]; a7 = fmaf(v.x, w0, a7); a7 = fmaf(v.y, w1, a7); a7 = fmaf(v.z, w2, a7); a7 = fmaf(v.w, w3, a7);
        }
        __half* up = U + (size_t)r0 * F_DIM + lane;
        up[0 * F_DIM] = __float2half(dinv[r0 + 0] * a0);
        up[1 * F_DIM] = __float2half(dinv[r0 + 1] * a1);
        up[2 * F_DIM] = __float2half(dinv[r0 + 2] * a2);
        up[3 * F_DIM] = __float2half(dinv[r0 + 3] * a3);
        up[4 * F_DIM] = __float2half(dinv[r0 + 4] * a4);
        up[5 * F_DIM] = __float2half(dinv[r0 + 5] * a5);
        up[6 * F_DIM] = __float2half(dinv[r0 + 6] * a6);
        up[7 * F_DIM] = __float2half(dinv[r0 + 7] * a7);
    }
}

// ---------------- aggregation: fp16 gather payload (128 B/row), wave per node,
// 8x8-lane groups (8 lanes x 16 B = one row), 4 edges/group in flight ----------------
// out[i] = epilogue( dinv[i]*(u[i] + sum_{src->i} u[src]) + b ), f32 accumulate
// MODE 0: relu -> out(f32 h) ; MODE 1: row L2-normalize -> out(d_out)

#define ADD8(ACC, V)                                              \
    {                                                             \
        const __half2* _hp = (const __half2*)&(V);                \
        float2 _f0 = __half22float2(_hp[0]);                      \
        float2 _f1 = __half22float2(_hp[1]);                      \
        float2 _f2 = __half22float2(_hp[2]);                      \
        float2 _f3 = __half22float2(_hp[3]);                      \
        ACC[0] += _f0.x; ACC[1] += _f0.y;                         \
        ACC[2] += _f1.x; ACC[3] += _f1.y;                         \
        ACC[4] += _f2.x; ACC[5] += _f2.y;                         \
        ACC[6] += _f3.x; ACC[7] += _f3.y;                         \
    }

template <int MODE>
__global__ __launch_bounds__(256) void k_agg(const __half* __restrict__ U, const int* __restrict__ srcs,
                                             const int* __restrict__ start, const float* __restrict__ dinv,
                                             const float* __restrict__ bias, float* __restrict__ out, int n) {
    int node = blockIdx.x * 4 + (threadIdx.x >> 6);
    if (node >= n) return;
    int lane = threadIdx.x & 63;
    int g = lane >> 3;       // edge sub-slot 0..7
    int t = lane & 7;        // 16B column slot within 128B row
    const float4* U4 = (const float4*)U;

    int s0 = start[node];
    int s1 = start[node + 1];

    float acc[8];
#pragma unroll
    for (int j = 0; j < 8; ++j) acc[j] = 0.f;
    if (g == 0) {                       // self-loop term
        float4 sv = U4[(size_t)node * 8 + t];
        ADD8(acc, sv);
    }

    float4 z = make_float4(0.f, 0.f, 0.f, 0.f);
    for (int p = s0; p < s1; p += 32) {
        int e0 = p + g, e1 = p + 8 + g, e2 = p + 16 + g, e3 = p + 24 + g;
        int i0 = (e0 < s1) ? srcs[e0] : 0;
        int i1 = (e1 < s1) ? srcs[e1] : 0;
        int i2 = (e2 < s1) ? srcs[e2] : 0;
        int i3 = (e3 < s1) ? srcs[e3] : 0;
        float4 v0 = (e0 < s1) ? U4[(size_t)i0 * 8 + t] : z;
        float4 v1 = (e1 < s1) ? U4[(size_t)i1 * 8 + t] : z;
        float4 v2 = (e2 < s1) ? U4[(size_t)i2 * 8 + t] : z;
        float4 v3 = (e3 < s1) ? U4[(size_t)i3 * 8 + t] : z;
        ADD8(acc, v0);
        ADD8(acc, v1);
        ADD8(acc, v2);
        ADD8(acc, v3);
    }

    // reduce across the 8 sub-slots (lanes ^8, ^16, ^32)
#pragma unroll
    for (int j = 0; j < 8; ++j) {
        acc[j] += __shfl_xor(acc[j], 8);
        acc[j] += __shfl_xor(acc[j], 16);
        acc[j] += __shfl_xor(acc[j], 32);
    }

    float di = dinv[node];
    const float4* b4 = (const float4*)bias;
    float4 bv0 = b4[2 * t], bv1 = b4[2 * t + 1];
    float v[8];
    v[0] = fmaf(di, acc[0], bv0.x); v[1] = fmaf(di, acc[1], bv0.y);
    v[2] = fmaf(di, acc[2], bv0.z); v[3] = fmaf(di, acc[3], bv0.w);
    v[4] = fmaf(di, acc[4], bv1.x); v[5] = fmaf(di, acc[5], bv1.y);
    v[6] = fmaf(di, acc[6], bv1.z); v[7] = fmaf(di, acc[7], bv1.w);

    if (MODE == 0) {
        if (g == 0) {
            float4 r0, r1;
            r0.x = fmaxf(v[0], 0.f); r0.y = fmaxf(v[1], 0.f);
            r0.z = fmaxf(v[2], 0.f); r0.w = fmaxf(v[3], 0.f);
            r1.x = fmaxf(v[4], 0.f); r1.y = fmaxf(v[5], 0.f);
            r1.z = fmaxf(v[6], 0.f); r1.w = fmaxf(v[7], 0.f);
            float4* o4 = (float4*)(out + (size_t)node * F_DIM);
            o4[2 * t] = r0; o4[2 * t + 1] = r1;
        }
    } else {
        float ss = 0.f;
#pragma unroll
        for (int j = 0; j < 8; ++j) ss = fmaf(v[j], v[j], ss);
        ss += __shfl_xor(ss, 1);
        ss += __shfl_xor(ss, 2);
        ss += __shfl_xor(ss, 4);
        float inv = 1.0f / fmaxf(sqrtf(ss), 1e-12f);
        if (g == 0) {
            float4 r0, r1;
            r0.x = v[0] * inv; r0.y = v[1] * inv; r0.z = v[2] * inv; r0.w = v[3] * inv;
            r1.x = v[4] * inv; r1.y = v[5] * inv; r1.z = v[6] * inv; r1.w = v[7] * inv;
            float4* o4 = (float4*)(out + (size_t)node * F_DIM);
            o4[2 * t] = r0; o4[2 * t + 1] = r1;
        }
    }
}

// ---------------- launch ----------------

extern "C" void kernel_launch(void* const* d_in, const int* in_sizes, int n_in,
                              void* d_out, int out_size, void* d_ws, size_t ws_size,
                              hipStream_t stream) {
    const float* x     = (const float*)d_in[0];
    const int*   ei    = (const int*)d_in[1];
    const float* W_pre = (const float*)d_in[2];
    const float* b_pre = (const float*)d_in[3];
    const float* W1    = (const float*)d_in[4];
    const float* b1    = (const float*)d_in[5];
    const float* Wh    = (const float*)d_in[6];
    const float* bh    = (const float*)d_in[7];
    const float* Wo    = (const float*)d_in[8];
    const float* bo    = (const float*)d_in[9];

    int n = in_sizes[0] / N_DIM;   // 100000
    int e = in_sizes[1] / 2;       // 1600000
    const int* srcIdx = ei;
    const int* dstIdx = ei + e;

    // workspace carve-out
    size_t off = 0;
    auto alloc = [&](size_t bytes) -> void* {
        void* p = (char*)d_ws + off;
        off += (bytes + 255) & ~(size_t)255;
        return p;
    };
    int*    cnt    = (int*)alloc((size_t)n * 4);
    int*    start  = (int*)alloc((size_t)(n + 1) * 4);
    int*    cursor = (int*)alloc((size_t)n * 4);
    float*  dinv   = (float*)alloc((size_t)n * 4);
    int*    bsum   = (int*)alloc(512 * 4);
    int*    srcs   = (int*)alloc((size_t)e * 4);
    float*  h      = (float*)alloc((size_t)n * F_DIM * 4);
    __half* u      = (__half*)alloc((size_t)n * F_DIM * 2);
    float*  Wc     = (float*)alloc((size_t)N_DIM * 64 * 4);
    float*  bb     = (float*)alloc(64 * 4);

    int nbN = (n + 255) / 256;
    int nchunk = (n + NXCD - 1) / NXCD;

    // 0. compose layer-1 weights: Wc = W_pre@W1, bb = b_pre@W1
    k_compose<<<1, 256, 0, stream>>>(W_pre, W1, b_pre, Wc, bb);

    // 1. degree count (without self loops), XCD-partitioned
    hipMemsetAsync(cnt, 0, (size_t)n * 4, stream);
    k_count<<<2048, 256, 0, stream>>>(dstIdx, cnt, e, nchunk);
    k_dinv<<<nbN, 256, 0, stream>>>(cnt, dinv, n);

    // 2. exclusive scan of counts -> start offsets, cursor copy
    k_scan1<<<nbN, 256, 0, stream>>>(cnt, start, bsum, n);
    k_scan2<<<1, 512, 0, stream>>>(bsum, nbN, start, n);
    k_scan3<<<nbN, 256, 0, stream>>>(start, cursor, bsum, n);

    // 3. place src indices sorted by dst (XCD-partitioned scatter)
    k_place<<<2048, 256, 0, stream>>>(srcIdx, dstIdx, cursor, srcs, e, nchunk);

    // 4. layer 1 (fused pre+linear): u = dinv*(x@Wc + bb)
    k_gemm_f<<<1280, 256, 0, stream>>>(x, Wc, bb, dinv, u, n);
    k_agg<0><<<(n + 3) / 4, 256, 0, stream>>>(u, srcs, start, dinv, b1, h, n);

    // 5. layer 2
    k_gemm_l<<<1280, 256, 0, stream>>>(h, Wh, dinv, u, n);
    k_agg<0><<<(n + 3) / 4, 256, 0, stream>>>(u, srcs, start, dinv, bh, h, n);

    // 6. layer 3 + final row L2 normalize -> d_out
    k_gemm_l<<<1280, 256, 0, stream>>>(h, Wo, dinv, u, n);
    k_agg<1><<<(n + 3) / 4, 256, 0, stream>>>(u, srcs, start, dinv, bo, (float*)d_out, n);
}

// Round 9
// 423.112 us; speedup vs baseline: 2.8404x; 1.3951x over previous
//
#include <hip/hip_runtime.h>
#include <hip/hip_fp16.h>

#define N_DIM 128
#define F_DIM 64
#define NXCD 8

typedef _Float16 half8 __attribute__((ext_vector_type(8)));
typedef float f32x4 __attribute__((ext_vector_type(4)));

// ---------------- weight composition: Wc = W_pre @ W1 (128x64), bb = b_pre @ W1 ----------------
__global__ __launch_bounds__(256) void k_compose(const float* __restrict__ Wpre, const float* __restrict__ W1,
                                                 const float* __restrict__ bpre, float* __restrict__ Wc,
                                                 float* __restrict__ bb) {
    int c = threadIdx.x & 63;
    int rq = threadIdx.x >> 6;                 // 0..3
    for (int r = rq; r < N_DIM; r += 4) {
        float acc = 0.f;
        for (int k = 0; k < 64; ++k) acc = fmaf(Wpre[r * 64 + k], W1[k * 64 + c], acc);
        Wc[r * 64 + c] = acc;
    }
    if (rq == 0) {
        float acc = 0.f;
        for (int k = 0; k < 64; ++k) acc = fmaf(bpre[k], W1[k * 64 + c], acc);
        bb[c] = acc;
    }
}

// ---------------- degree / sort kernels ----------------

__global__ __launch_bounds__(256) void k_count(const int* __restrict__ dst, int* __restrict__ cnt,
                                               int e, int nchunk) {
    int p = blockIdx.x & (NXCD - 1);
    int q = blockIdx.x >> 3;
    int nq = gridDim.x >> 3;
    int lo = p * nchunk, hi = lo + nchunk;
    for (int i = q * 256 + threadIdx.x; i < e; i += nq * 256) {
        int d = dst[i];
        if (d >= lo && d < hi) atomicAdd(&cnt[d], 1);
    }
}

__global__ __launch_bounds__(256) void k_dinv(const int* __restrict__ cnt, float* __restrict__ dinv, int n) {
    int i = blockIdx.x * 256 + threadIdx.x;
    if (i < n) dinv[i] = rsqrtf((float)cnt[i] + 1.0f);   // +1 self loop
}

__global__ __launch_bounds__(256) void k_scan1(const int* __restrict__ cnt, int* __restrict__ excl,
                                               int* __restrict__ bsum, int n) {
    __shared__ int s[256];
    int t = threadIdx.x;
    int i = blockIdx.x * 256 + t;
    int v = (i < n) ? cnt[i] : 0;
    s[t] = v;
    __syncthreads();
    for (int off = 1; off < 256; off <<= 1) {
        int x = (t >= off) ? s[t - off] : 0;
        __syncthreads();
        s[t] += x;
        __syncthreads();
    }
    if (i < n) excl[i] = s[t] - v;
    if (t == 255) bsum[blockIdx.x] = s[255];
}

__global__ __launch_bounds__(512) void k_scan2(int* __restrict__ bsum, int nb, int* __restrict__ start, int n) {
    __shared__ int s[512];
    int t = threadIdx.x;
    int v = (t < nb) ? bsum[t] : 0;
    s[t] = v;
    __syncthreads();
    for (int off = 1; off < 512; off <<= 1) {
        int x = (t >= off) ? s[t - off] : 0;
        __syncthreads();
        s[t] += x;
        __syncthreads();
    }
    if (t < nb) bsum[t] = s[t] - v;     // exclusive block offsets
    if (t == 511) start[n] = s[511];    // total edge count
}

__global__ __launch_bounds__(256) void k_scan3(int* __restrict__ start, int* __restrict__ cursor,
                                               const int* __restrict__ bsum, int n) {
    int i = blockIdx.x * 256 + threadIdx.x;
    if (i < n) {
        int v = start[i] + bsum[blockIdx.x];
        start[i] = v;
        cursor[i] = v;
    }
}

__global__ __launch_bounds__(256) void k_place(const int* __restrict__ src, const int* __restrict__ dst,
                                               int* __restrict__ cursor, int* __restrict__ srcs,
                                               int e, int nchunk) {
    int p = blockIdx.x & (NXCD - 1);
    int q = blockIdx.x >> 3;
    int nq = gridDim.x >> 3;
    int lo = p * nchunk, hi = lo + nchunk;
    for (int i = q * 256 + threadIdx.x; i < e; i += nq * 256) {
        int d = dst[i];
        if (d >= lo && d < hi) {
            int slot = atomicAdd(&cursor[d], 1);
            srcs[slot] = src[i];
        }
    }
}

// ---------------- MFMA GEMMs ----------------
// mfma_f32_16x16x32_f16 fragment layouts (m89/m91-verified family):
//   A: lane holds A[row = lane&15][k = (lane>>4)*8 + i], i=0..7 (contiguous k)
//   B: lane holds B[k = (lane>>4)*8 + i][col = lane&15]
//   C/D: col = lane&15, row = (lane>>4)*4 + reg
// B is pre-packed to fragment order in LDS: frag[(s*4+c)*64 + lane] -> ds_read_b128 at lane*16,
// consecutive lanes -> conflict-free.

// pack W (f32 [K][64]) into LDS fragments; S = K/32 k-steps
template <int S>
__device__ inline void pack_w(const float* __restrict__ W, half8* __restrict__ Bf) {
    for (int f = threadIdx.x; f < S * 4 * 64; f += 256) {
        int l = f & 63, c = (f >> 6) & 3, s = f >> 8;
        int kbase = s * 32 + ((l >> 4) << 3);
        int col = c * 16 + (l & 15);
        half8 pk;
#pragma unroll
        for (int i = 0; i < 8; ++i) pk[i] = (_Float16)W[(kbase + i) * 64 + col];
        Bf[f] = pk;
    }
    __syncthreads();
}

// u = dinv * (x @ Wc + bb)   (N x 128)f32 @ (128 x 64), fp16 out  [layer-1 fused]
__global__ __launch_bounds__(256) void k_gemm_f(const float* __restrict__ X, const float* __restrict__ Wc,
                                                const float* __restrict__ bb, const float* __restrict__ dinv,
                                                __half* __restrict__ U, int n) {
    __shared__ half8 Bf[4 * 4 * 64];       // 16 KB
    pack_w<4>(Wc, Bf);
    int lane = threadIdx.x & 63;
    int row = lane & 15, kq = lane >> 4;
    float bbv0 = bb[0 * 16 + row], bbv1 = bb[1 * 16 + row], bbv2 = bb[2 * 16 + row], bbv3 = bb[3 * 16 + row];
    int gw = (blockIdx.x * 256 + threadIdx.x) >> 6;
    int nw = (gridDim.x * 256) >> 6;
    int ntile = n >> 4;
    for (int tile = gw; tile < ntile; tile += nw) {
        int r0 = tile << 4;
        const float* xp = X + (size_t)(r0 + row) * N_DIM + (kq << 3);
        f32x4 ac0 = {0.f, 0.f, 0.f, 0.f}, ac1 = ac0, ac2 = ac0, ac3 = ac0;
#pragma unroll
        for (int s = 0; s < 4; ++s) {
            float4 lo = *(const float4*)(xp + s * 32);
            float4 hi = *(const float4*)(xp + s * 32 + 4);
            half8 a;
            a[0] = (_Float16)lo.x; a[1] = (_Float16)lo.y; a[2] = (_Float16)lo.z; a[3] = (_Float16)lo.w;
            a[4] = (_Float16)hi.x; a[5] = (_Float16)hi.y; a[6] = (_Float16)hi.z; a[7] = (_Float16)hi.w;
            ac0 = __builtin_amdgcn_mfma_f32_16x16x32_f16(a, Bf[(s * 4 + 0) * 64 + lane], ac0, 0, 0, 0);
            ac1 = __builtin_amdgcn_mfma_f32_16x16x32_f16(a, Bf[(s * 4 + 1) * 64 + lane], ac1, 0, 0, 0);
            ac2 = __builtin_amdgcn_mfma_f32_16x16x32_f16(a, Bf[(s * 4 + 2) * 64 + lane], ac2, 0, 0, 0);
            ac3 = __builtin_amdgcn_mfma_f32_16x16x32_f16(a, Bf[(s * 4 + 3) * 64 + lane], ac3, 0, 0, 0);
        }
        int rbase = r0 + (kq << 2);
        float d0 = dinv[rbase + 0], d1 = dinv[rbase + 1], d2 = dinv[rbase + 2], d3 = dinv[rbase + 3];
        __half* up = U + (size_t)rbase * F_DIM + row;
        up[0 * F_DIM +  0] = __float2half(d0 * (ac0[0] + bbv0));
        up[1 * F_DIM +  0] = __float2half(d1 * (ac0[1] + bbv0));
        up[2 * F_DIM +  0] = __float2half(d2 * (ac0[2] + bbv0));
        up[3 * F_DIM +  0] = __float2half(d3 * (ac0[3] + bbv0));
        up[0 * F_DIM + 16] = __float2half(d0 * (ac1[0] + bbv1));
        up[1 * F_DIM + 16] = __float2half(d1 * (ac1[1] + bbv1));
        up[2 * F_DIM + 16] = __float2half(d2 * (ac1[2] + bbv1));
        up[3 * F_DIM + 16] = __float2half(d3 * (ac1[3] + bbv1));
        up[0 * F_DIM + 32] = __float2half(d0 * (ac2[0] + bbv2));
        up[1 * F_DIM + 32] = __float2half(d1 * (ac2[1] + bbv2));
        up[2 * F_DIM + 32] = __float2half(d2 * (ac2[2] + bbv2));
        up[3 * F_DIM + 32] = __float2half(d3 * (ac2[3] + bbv2));
        up[0 * F_DIM + 48] = __float2half(d0 * (ac3[0] + bbv3));
        up[1 * F_DIM + 48] = __float2half(d1 * (ac3[1] + bbv3));
        up[2 * F_DIM + 48] = __float2half(d2 * (ac3[2] + bbv3));
        up[3 * F_DIM + 48] = __float2half(d3 * (ac3[3] + bbv3));
    }
}

// u = dinv * (h @ W)   (N x 64)fp16 @ (64 x 64), fp16 out
__global__ __launch_bounds__(256) void k_gemm_l(const __half* __restrict__ H, const float* __restrict__ W,
                                                const float* __restrict__ dinv, __half* __restrict__ U, int n) {
    __shared__ half8 Bf[2 * 4 * 64];       // 8 KB
    pack_w<2>(W, Bf);
    int lane = threadIdx.x & 63;
    int row = lane & 15, kq = lane >> 4;
    int gw = (blockIdx.x * 256 + threadIdx.x) >> 6;
    int nw = (gridDim.x * 256) >> 6;
    int ntile = n >> 4;
    for (int tile = gw; tile < ntile; tile += nw) {
        int r0 = tile << 4;
        const _Float16* hp = (const _Float16*)H + (size_t)(r0 + row) * F_DIM + (kq << 3);
        half8 a0 = *(const half8*)(hp);
        half8 a1 = *(const half8*)(hp + 32);
        f32x4 ac0 = {0.f, 0.f, 0.f, 0.f}, ac1 = ac0, ac2 = ac0, ac3 = ac0;
        ac0 = __builtin_amdgcn_mfma_f32_16x16x32_f16(a0, Bf[0 * 64 + lane], ac0, 0, 0, 0);
        ac1 = __builtin_amdgcn_mfma_f32_16x16x32_f16(a0, Bf[1 * 64 + lane], ac1, 0, 0, 0);
        ac2 = __builtin_amdgcn_mfma_f32_16x16x32_f16(a0, Bf[2 * 64 + lane], ac2, 0, 0, 0);
        ac3 = __builtin_amdgcn_mfma_f32_16x16x32_f16(a0, Bf[3 * 64 + lane], ac3, 0, 0, 0);
        ac0 = __builtin_amdgcn_mfma_f32_16x16x32_f16(a1, Bf[4 * 64 + lane], ac0, 0, 0, 0);
        ac1 = __builtin_amdgcn_mfma_f32_16x16x32_f16(a1, Bf[5 * 64 + lane], ac1, 0, 0, 0);
        ac2 = __builtin_amdgcn_mfma_f32_16x16x32_f16(a1, Bf[6 * 64 + lane], ac2, 0, 0, 0);
        ac3 = __builtin_amdgcn_mfma_f32_16x16x32_f16(a1, Bf[7 * 64 + lane], ac3, 0, 0, 0);
        int rbase = r0 + (kq << 2);
        float d0 = dinv[rbase + 0], d1 = dinv[rbase + 1], d2 = dinv[rbase + 2], d3 = dinv[rbase + 3];
        __half* up = U + (size_t)rbase * F_DIM + row;
        up[0 * F_DIM +  0] = __float2half(d0 * ac0[0]);
        up[1 * F_DIM +  0] = __float2half(d1 * ac0[1]);
        up[2 * F_DIM +  0] = __float2half(d2 * ac0[2]);
        up[3 * F_DIM +  0] = __float2half(d3 * ac0[3]);
        up[0 * F_DIM + 16] = __float2half(d0 * ac1[0]);
        up[1 * F_DIM + 16] = __float2half(d1 * ac1[1]);
        up[2 * F_DIM + 16] = __float2half(d2 * ac1[2]);
        up[3 * F_DIM + 16] = __float2half(d3 * ac1[3]);
        up[0 * F_DIM + 32] = __float2half(d0 * ac2[0]);
        up[1 * F_DIM + 32] = __float2half(d1 * ac2[1]);
        up[2 * F_DIM + 32] = __float2half(d2 * ac2[2]);
        up[3 * F_DIM + 32] = __float2half(d3 * ac2[3]);
        up[0 * F_DIM + 48] = __float2half(d0 * ac3[0]);
        up[1 * F_DIM + 48] = __float2half(d1 * ac3[1]);
        up[2 * F_DIM + 48] = __float2half(d2 * ac3[2]);
        up[3 * F_DIM + 48] = __float2half(d3 * ac3[3]);
    }
}

// ---------------- aggregation: fp16 gather payload (128 B/row), wave per node,
// 8x8-lane groups, 4 edges/group in flight; MODE 0 writes fp16 h, MODE 1 f32 d_out ----------------

#define ADD8(ACC, V)                                              \
    {                                                             \
        const __half2* _hp = (const __half2*)&(V);                \
        float2 _f0 = __half22float2(_hp[0]);                      \
        float2 _f1 = __half22float2(_hp[1]);                      \
        float2 _f2 = __half22float2(_hp[2]);                      \
        float2 _f3 = __half22float2(_hp[3]);                      \
        ACC[0] += _f0.x; ACC[1] += _f0.y;                         \
        ACC[2] += _f1.x; ACC[3] += _f1.y;                         \
        ACC[4] += _f2.x; ACC[5] += _f2.y;                         \
        ACC[6] += _f3.x; ACC[7] += _f3.y;                         \
    }

template <int MODE>
__global__ __launch_bounds__(256) void k_agg(const __half* __restrict__ U, const int* __restrict__ srcs,
                                             const int* __restrict__ start, const float* __restrict__ dinv,
                                             const float* __restrict__ bias, void* __restrict__ outp, int n) {
    int node = blockIdx.x * 4 + (threadIdx.x >> 6);
    if (node >= n) return;
    int lane = threadIdx.x & 63;
    int g = lane >> 3;       // edge sub-slot 0..7
    int t = lane & 7;        // 16B column slot within 128B row
    const float4* U4 = (const float4*)U;

    int s0 = start[node];
    int s1 = start[node + 1];

    float acc[8];
#pragma unroll
    for (int j = 0; j < 8; ++j) acc[j] = 0.f;
    if (g == 0) {                       // self-loop term
        float4 sv = U4[(size_t)node * 8 + t];
        ADD8(acc, sv);
    }

    float4 z = make_float4(0.f, 0.f, 0.f, 0.f);
    for (int p = s0; p < s1; p += 32) {
        int e0 = p + g, e1 = p + 8 + g, e2 = p + 16 + g, e3 = p + 24 + g;
        int i0 = (e0 < s1) ? srcs[e0] : 0;
        int i1 = (e1 < s1) ? srcs[e1] : 0;
        int i2 = (e2 < s1) ? srcs[e2] : 0;
        int i3 = (e3 < s1) ? srcs[e3] : 0;
        float4 v0 = (e0 < s1) ? U4[(size_t)i0 * 8 + t] : z;
        float4 v1 = (e1 < s1) ? U4[(size_t)i1 * 8 + t] : z;
        float4 v2 = (e2 < s1) ? U4[(size_t)i2 * 8 + t] : z;
        float4 v3 = (e3 < s1) ? U4[(size_t)i3 * 8 + t] : z;
        ADD8(acc, v0);
        ADD8(acc, v1);
        ADD8(acc, v2);
        ADD8(acc, v3);
    }

#pragma unroll
    for (int j = 0; j < 8; ++j) {
        acc[j] += __shfl_xor(acc[j], 8);
        acc[j] += __shfl_xor(acc[j], 16);
        acc[j] += __shfl_xor(acc[j], 32);
    }

    float di = dinv[node];
    const float4* b4 = (const float4*)bias;
    float4 bv0 = b4[2 * t], bv1 = b4[2 * t + 1];
    float v[8];
    v[0] = fmaf(di, acc[0], bv0.x); v[1] = fmaf(di, acc[1], bv0.y);
    v[2] = fmaf(di, acc[2], bv0.z); v[3] = fmaf(di, acc[3], bv0.w);
    v[4] = fmaf(di, acc[4], bv1.x); v[5] = fmaf(di, acc[5], bv1.y);
    v[6] = fmaf(di, acc[6], bv1.z); v[7] = fmaf(di, acc[7], bv1.w);

    if (MODE == 0) {
        if (g == 0) {
            __half hr[8];
#pragma unroll
            for (int j = 0; j < 8; ++j) hr[j] = __float2half(fmaxf(v[j], 0.f));
            *(float4*)((__half*)outp + (size_t)node * F_DIM + t * 8) = *(float4*)hr;
        }
    } else {
        float ss = 0.f;
#pragma unroll
        for (int j = 0; j < 8; ++j) ss = fmaf(v[j], v[j], ss);
        ss += __shfl_xor(ss, 1);
        ss += __shfl_xor(ss, 2);
        ss += __shfl_xor(ss, 4);
        float inv = 1.0f / fmaxf(sqrtf(ss), 1e-12f);
        if (g == 0) {
            float4 r0, r1;
            r0.x = v[0] * inv; r0.y = v[1] * inv; r0.z = v[2] * inv; r0.w = v[3] * inv;
            r1.x = v[4] * inv; r1.y = v[5] * inv; r1.z = v[6] * inv; r1.w = v[7] * inv;
            float4* o4 = (float4*)((float*)outp + (size_t)node * F_DIM);
            o4[2 * t] = r0; o4[2 * t + 1] = r1;
        }
    }
}

// ---------------- launch ----------------

extern "C" void kernel_launch(void* const* d_in, const int* in_sizes, int n_in,
                              void* d_out, int out_size, void* d_ws, size_t ws_size,
                              hipStream_t stream) {
    const float* x     = (const float*)d_in[0];
    const int*   ei    = (const int*)d_in[1];
    const float* W_pre = (const float*)d_in[2];
    const float* b_pre = (const float*)d_in[3];
    const float* W1    = (const float*)d_in[4];
    const float* b1    = (const float*)d_in[5];
    const float* Wh    = (const float*)d_in[6];
    const float* bh    = (const float*)d_in[7];
    const float* Wo    = (const float*)d_in[8];
    const float* bo    = (const float*)d_in[9];

    int n = in_sizes[0] / N_DIM;   // 100000
    int e = in_sizes[1] / 2;       // 1600000
    const int* srcIdx = ei;
    const int* dstIdx = ei + e;

    size_t off = 0;
    auto alloc = [&](size_t bytes) -> void* {
        void* p = (char*)d_ws + off;
        off += (bytes + 255) & ~(size_t)255;
        return p;
    };
    int*    cnt    = (int*)alloc((size_t)n * 4);
    int*    start  = (int*)alloc((size_t)(n + 1) * 4);
    int*    cursor = (int*)alloc((size_t)n * 4);
    float*  dinv   = (float*)alloc((size_t)n * 4);
    int*    bsum   = (int*)alloc(512 * 4);
    int*    srcs   = (int*)alloc((size_t)e * 4);
    __half* h      = (__half*)alloc((size_t)n * F_DIM * 2);
    __half* u      = (__half*)alloc((size_t)n * F_DIM * 2);
    float*  Wc     = (float*)alloc((size_t)N_DIM * 64 * 4);
    float*  bb     = (float*)alloc(64 * 4);

    int nbN = (n + 255) / 256;
    int nchunk = (n + NXCD - 1) / NXCD;

    // 0. compose layer-1 weights: Wc = W_pre@W1, bb = b_pre@W1
    k_compose<<<1, 256, 0, stream>>>(W_pre, W1, b_pre, Wc, bb);

    // 1. degree count (without self loops), XCD-partitioned
    hipMemsetAsync(cnt, 0, (size_t)n * 4, stream);
    k_count<<<2048, 256, 0, stream>>>(dstIdx, cnt, e, nchunk);
    k_dinv<<<nbN, 256, 0, stream>>>(cnt, dinv, n);

    // 2. exclusive scan of counts -> start offsets, cursor copy
    k_scan1<<<nbN, 256, 0, stream>>>(cnt, start, bsum, n);
    k_scan2<<<1, 512, 0, stream>>>(bsum, nbN, start, n);
    k_scan3<<<nbN, 256, 0, stream>>>(start, cursor, bsum, n);

    // 3. place src indices sorted by dst (XCD-partitioned scatter)
    k_place<<<2048, 256, 0, stream>>>(srcIdx, dstIdx, cursor, srcs, e, nchunk);

    // 4. layer 1 (fused pre+linear, MFMA): u = dinv*(x@Wc + bb)
    k_gemm_f<<<800, 256, 0, stream>>>(x, Wc, bb, dinv, u, n);
    k_agg<0><<<(n + 3) / 4, 256, 0, stream>>>(u, srcs, start, dinv, b1, h, n);

    // 5. layer 2 (MFMA)
    k_gemm_l<<<800, 256, 0, stream>>>(h, Wh, dinv, u, n);
    k_agg<0><<<(n + 3) / 4, 256, 0, stream>>>(u, srcs, start, dinv, bh, h, n);

    // 6. layer 3 (MFMA) + final row L2 normalize -> d_out
    k_gemm_l<<<800, 256, 0, stream>>>(h, Wo, dinv, u, n);
    k_agg<1><<<(n + 3) / 4, 256, 0, stream>>>(u, srcs, start, dinv, bo, d_out, n);
}